// Round 13
// baseline (1886.727 us; speedup 1.0000x reference)
//
#include <hip/hip_runtime.h>
#include <math.h>

#define DD 256
#define DFFN 1024
#define LQT 12240
#define BB 2
#define MROWS (BB * LQT)   // 24480

typedef __attribute__((ext_vector_type(8))) short short8v;
typedef __attribute__((ext_vector_type(4))) float floatx4;

__device__ __forceinline__ unsigned short f2bf(float x) {
    unsigned int u = __builtin_bit_cast(unsigned int, x);
    u = (u + 0x7fffu + ((u >> 16) & 1u)) >> 16;
    return (unsigned short)u;
}
__device__ __forceinline__ float bf2f(unsigned short h) {
    unsigned int u = ((unsigned int)h) << 16;
    return __builtin_bit_cast(float, u);
}

// aux: cache-policy bits (gfx950: bit1 = NT). NT for read-once streams.
template<int AUX>
__device__ __forceinline__ void gload16x(const unsigned short* g, unsigned short* lds) {
    __builtin_amdgcn_global_load_lds(
        (const __attribute__((address_space(1))) unsigned int*)g,
        (__attribute__((address_space(3))) unsigned int*)lds, 16, 0, AUX);
}
__device__ __forceinline__ void gload16(const unsigned short* g, unsigned short* lds) {
    gload16x<0>(g, lds);
}

__device__ __forceinline__ void level_of(int q, int& lvl, int& start, int& S) {
    if (q < 9216)       { lvl = 0; start = 0;     S = 96; }
    else if (q < 11520) { lvl = 1; start = 9216;  S = 48; }
    else if (q < 12096) { lvl = 2; start = 11520; S = 24; }
    else                { lvl = 3; start = 12096; S = 12; }
}

// ---------------------------------------------------------------------------
// Merged QKV projection: grid (383, 5), 256t, 2-phase double-buffer.
// ---------------------------------------------------------------------------
__global__ __launch_bounds__(256)
void gemm_qkv(const unsigned short* __restrict__ Aq,
              const unsigned short* __restrict__ Asr,
              const unsigned short* __restrict__ Woff,
              const unsigned short* __restrict__ Waw,
              const unsigned short* __restrict__ Wval,
              const float* __restrict__ boff, const float* __restrict__ baw,
              const float* __restrict__ bval,
              float* __restrict__ awbo, unsigned short* __restrict__ offo,
              unsigned short* __restrict__ valo)
{
    __shared__ alignas(16) unsigned short As[2][4][64][8];
    __shared__ alignas(16) unsigned short Bs[2][4][128][8];
    const int t = threadIdx.x;
    const int m0 = blockIdx.x * 64;
    const int y = blockIdx.y;
    const unsigned short* A; const unsigned short* Wb; const float* bi;
    int nb, mode;
    if (y < 3) {
        A = Aq;
        if (y < 2) { Wb = Woff; bi = boff; nb = y * 128; mode = 0; }
        else       { Wb = Waw;  bi = baw;  nb = 0;       mode = 1; }
    } else {
        A = Asr; Wb = Wval; bi = bval; nb = (y - 3) * 128; mode = 2;
    }
    const int wv = __builtin_amdgcn_readfirstlane(t >> 6);
    const int lane = t & 63;
    const int wm = wv >> 1, wn = wv & 1;
    const int kb = lane >> 4, lr = lane & 15;

    const int ar = min(m0 + lane, MROWS - 1);
    const unsigned short* gA  = A  + (long)ar * 256 + wv * 8;
    const unsigned short* gB0 = Wb + (long)(nb + lane) * 256 + wv * 8;
    const unsigned short* gB1 = Wb + (long)(nb + 64 + lane) * 256 + wv * 8;

    floatx4 acc[2][4];
    #pragma unroll
    for (int m = 0; m < 2; ++m)
        #pragma unroll
        for (int n = 0; n < 4; ++n)
            acc[m][n] = (floatx4){0.f, 0.f, 0.f, 0.f};

    gload16(gA,  &As[0][wv][0][0]);
    gload16(gB0, &Bs[0][wv][0][0]);
    gload16(gB1, &Bs[0][wv][64][0]);
    gA += 32; gB0 += 32; gB1 += 32;
    __syncthreads();

    #pragma unroll
    for (int kt = 0; kt < 8; ++kt) {
        const int cur = kt & 1;
        if (kt < 7) {
            gload16(gA,  &As[cur ^ 1][wv][0][0]);
            gload16(gB0, &Bs[cur ^ 1][wv][0][0]);
            gload16(gB1, &Bs[cur ^ 1][wv][64][0]);
            gA += 32; gB0 += 32; gB1 += 32;
        }
        short8v av[2], bv[4];
        #pragma unroll
        for (int m = 0; m < 2; ++m)
            av[m] = *(const short8v*)&As[cur][kb][wm * 32 + m * 16 + lr][0];
        #pragma unroll
        for (int n = 0; n < 4; ++n)
            bv[n] = *(const short8v*)&Bs[cur][kb][wn * 64 + n * 16 + lr][0];
        #pragma unroll
        for (int m = 0; m < 2; ++m)
            #pragma unroll
            for (int n = 0; n < 4; ++n)
                acc[m][n] = __builtin_amdgcn_mfma_f32_16x16x32_bf16(
                    av[m], bv[n], acc[m][n], 0, 0, 0);
        __syncthreads();
    }

    const int lh = lane >> 4;
    #pragma unroll
    for (int m = 0; m < 2; ++m) {
        const int row0 = m0 + wm * 32 + m * 16 + lh * 4;
        #pragma unroll
        for (int n = 0; n < 4; ++n) {
            const int col = nb + wn * 64 + n * 16 + lr;
            const float b = bi[col];
            #pragma unroll
            for (int r = 0; r < 4; ++r) {
                const int row = row0 + r;
                if (row >= MROWS) continue;
                const float v = acc[m][n][r] + b;
                if (mode == 0)      offo[(long)row * 256 + col] = f2bf(v);
                else if (mode == 1) awbo[(long)row * 128 + col] = v;
                else                valo[(long)row * 256 + col] = f2bf(v);
            }
        }
    }
}

// ---------------------------------------------------------------------------
// BM=64 x BN=128 bf16 GEMM (input projections only, setup), 2-phase
// ---------------------------------------------------------------------------
__global__ __launch_bounds__(256)
void gemm64(const unsigned short* __restrict__ A, long aZ,
            const unsigned short* __restrict__ W,
            const float* __restrict__ bias,
            float* __restrict__ Cf, long cZ,
            int M, int N, int K)
{
    __shared__ alignas(16) unsigned short As[2][4][64][8];
    __shared__ alignas(16) unsigned short Bs[2][4][128][8];
    const int t = threadIdx.x;
    const int z = blockIdx.z;
    A  += (long)z * aZ;
    Cf += (long)z * cZ;
    const int m0 = blockIdx.x * 64;
    const int n0 = blockIdx.y * 128;
    const int wv = __builtin_amdgcn_readfirstlane(t >> 6);
    const int lane = t & 63;
    const int wm = wv >> 1, wn = wv & 1;
    const int kb = lane >> 4, lr = lane & 15;

    const int ar = min(m0 + lane, M - 1);
    const unsigned short* gA  = A + (long)ar * K + wv * 8;
    const unsigned short* gB0 = W + (long)(n0 + lane) * K + wv * 8;
    const unsigned short* gB1 = W + (long)(n0 + 64 + lane) * K + wv * 8;

    floatx4 acc[2][4];
    #pragma unroll
    for (int m = 0; m < 2; ++m)
        #pragma unroll
        for (int n = 0; n < 4; ++n)
            acc[m][n] = (floatx4){0.f, 0.f, 0.f, 0.f};

    gload16(gA,  &As[0][wv][0][0]);
    gload16(gB0, &Bs[0][wv][0][0]);
    gload16(gB1, &Bs[0][wv][64][0]);
    gA += 32; gB0 += 32; gB1 += 32;
    __syncthreads();

    const int nk = K >> 5;
    for (int kt = 0; kt < nk; ++kt) {
        const int cur = kt & 1;
        if (kt + 1 < nk) {
            gload16(gA,  &As[cur ^ 1][wv][0][0]);
            gload16(gB0, &Bs[cur ^ 1][wv][0][0]);
            gload16(gB1, &Bs[cur ^ 1][wv][64][0]);
            gA += 32; gB0 += 32; gB1 += 32;
        }
        short8v av[2], bv[4];
        #pragma unroll
        for (int m = 0; m < 2; ++m)
            av[m] = *(const short8v*)&As[cur][kb][wm * 32 + m * 16 + lr][0];
        #pragma unroll
        for (int n = 0; n < 4; ++n)
            bv[n] = *(const short8v*)&Bs[cur][kb][wn * 64 + n * 16 + lr][0];
        #pragma unroll
        for (int m = 0; m < 2; ++m)
            #pragma unroll
            for (int n = 0; n < 4; ++n)
                acc[m][n] = __builtin_amdgcn_mfma_f32_16x16x32_bf16(
                    av[m], bv[n], acc[m][n], 0, 0, 0);
        __syncthreads();
    }

    const int lh = lane >> 4;
    #pragma unroll
    for (int m = 0; m < 2; ++m) {
        const int row0 = m0 + wm * 32 + m * 16 + lh * 4;
        #pragma unroll
        for (int n = 0; n < 4; ++n) {
            const int col = n0 + wn * 64 + n * 16 + lr;
            const float b = bias[col];
            #pragma unroll
            for (int r = 0; r < 4; ++r) {
                const int row = row0 + r;
                if (row >= M) continue;
                Cf[(long)row * N + col] = acc[m][n][r] + b;
            }
        }
    }
}

// ---------------------------------------------------------------------------
// FFN1 BM=128 x BN=128 (relu -> bf16), 2-phase; hid stores non-temporal.
// ---------------------------------------------------------------------------
__global__ __launch_bounds__(256)
void gemm128(const unsigned short* __restrict__ A,
             const unsigned short* __restrict__ W,
             const float* __restrict__ bias, unsigned short* __restrict__ Ch,
             int M, int N, int K)
{
    __shared__ alignas(16) unsigned short As[2][4][128][8];
    __shared__ alignas(16) unsigned short Bs[2][4][128][8];
    const int t = threadIdx.x;
    const int m0 = blockIdx.x * 128;
    const int n0 = blockIdx.y * 128;
    const int wv = __builtin_amdgcn_readfirstlane(t >> 6);
    const int lane = t & 63;
    const int wm = wv >> 1, wn = wv & 1;
    const int kb = lane >> 4, lr = lane & 15;

    const int r0 = min(m0 + lane, M - 1);
    const int r1 = min(m0 + 64 + lane, M - 1);
    const unsigned short* gA0 = A + (long)r0 * K + wv * 8;
    const unsigned short* gA1 = A + (long)r1 * K + wv * 8;
    const unsigned short* gB0 = W + (long)(n0 + lane) * K + wv * 8;
    const unsigned short* gB1 = W + (long)(n0 + 64 + lane) * K + wv * 8;

    floatx4 acc[4][4];
    #pragma unroll
    for (int m = 0; m < 4; ++m)
        #pragma unroll
        for (int n = 0; n < 4; ++n)
            acc[m][n] = (floatx4){0.f, 0.f, 0.f, 0.f};

    gload16(gA0, &As[0][wv][0][0]);
    gload16(gA1, &As[0][wv][64][0]);
    gload16(gB0, &Bs[0][wv][0][0]);
    gload16(gB1, &Bs[0][wv][64][0]);
    gA0 += 32; gA1 += 32; gB0 += 32; gB1 += 32;
    __syncthreads();

    const int nk = K >> 5;
    for (int kt = 0; kt < nk; ++kt) {
        const int cur = kt & 1;
        if (kt + 1 < nk) {
            gload16(gA0, &As[cur ^ 1][wv][0][0]);
            gload16(gA1, &As[cur ^ 1][wv][64][0]);
            gload16(gB0, &Bs[cur ^ 1][wv][0][0]);
            gload16(gB1, &Bs[cur ^ 1][wv][64][0]);
            gA0 += 32; gA1 += 32; gB0 += 32; gB1 += 32;
        }
        short8v av[4], bv[4];
        #pragma unroll
        for (int m = 0; m < 4; ++m)
            av[m] = *(const short8v*)&As[cur][kb][wm * 64 + m * 16 + lr][0];
        #pragma unroll
        for (int n = 0; n < 4; ++n)
            bv[n] = *(const short8v*)&Bs[cur][kb][wn * 64 + n * 16 + lr][0];
        #pragma unroll
        for (int m = 0; m < 4; ++m)
            #pragma unroll
            for (int n = 0; n < 4; ++n)
                acc[m][n] = __builtin_amdgcn_mfma_f32_16x16x32_bf16(
                    av[m], bv[n], acc[m][n], 0, 0, 0);
        __syncthreads();
    }

    const int lh = lane >> 4;
    #pragma unroll
    for (int m = 0; m < 4; ++m) {
        const int row0 = m0 + wm * 64 + m * 16 + lh * 4;
        #pragma unroll
        for (int n = 0; n < 4; ++n) {
            const int col = n0 + wn * 64 + n * 16 + lr;
            const float b = bias[col];
            #pragma unroll
            for (int r = 0; r < 4; ++r) {
                const int row = row0 + r;
                if (row >= M) continue;
                __builtin_nontemporal_store(
                    f2bf(fmaxf(acc[m][n][r] + b, 0.f)),
                    &Ch[(long)row * N + col]);
            }
        }
    }
}

// ---------------------------------------------------------------------------
// BM=32 x BN=256 GEMM + bias + bf16-residual + LayerNorm epilogue.
// A (activation, read-once stream) loaded with NT to protect W's L2 residency.
// ---------------------------------------------------------------------------
__global__ __launch_bounds__(256)
void gemm_ln(const unsigned short* __restrict__ A,
             const unsigned short* __restrict__ W,
             const float* __restrict__ bias, const unsigned short* R,
             const float* __restrict__ lg, const float* __restrict__ lb,
             float* outf, unsigned short* outh,
             const float* __restrict__ pos, unsigned short* __restrict__ qout,
             int M, int K)
{
    __shared__ alignas(16) unsigned short As[2][4][32][8];
    __shared__ alignas(16) unsigned short Bs[2][4][256][8];
    __shared__ float red[32][4][2];
    __shared__ float smean[32], sinv[32];
    const int t = threadIdx.x;
    const int m0 = blockIdx.x * 32;
    const int wv = __builtin_amdgcn_readfirstlane(t >> 6);
    const int lane = t & 63;
    const int kb = lane >> 4, lr = lane & 15;
    const int lh = kb;

    const unsigned short* gA = A + (long)(m0 + (lane & 31)) * K
                                 + (wv * 2 + (lane >> 5)) * 8;
    const unsigned short* gB0 = W + (long)lane * K + wv * 8;
    const unsigned short* gB1 = W + (long)(64 + lane) * K + wv * 8;
    const unsigned short* gB2 = W + (long)(128 + lane) * K + wv * 8;
    const unsigned short* gB3 = W + (long)(192 + lane) * K + wv * 8;

    floatx4 acc[2][4];
    #pragma unroll
    for (int m = 0; m < 2; ++m)
        #pragma unroll
        for (int n = 0; n < 4; ++n)
            acc[m][n] = (floatx4){0.f, 0.f, 0.f, 0.f};

    if (wv < 2) gload16x<2>(gA, &As[0][wv * 2][0][0]);   // NT: stream
    gload16(gB0, &Bs[0][wv][0][0]);
    gload16(gB1, &Bs[0][wv][64][0]);
    gload16(gB2, &Bs[0][wv][128][0]);
    gload16(gB3, &Bs[0][wv][192][0]);
    gA += 32; gB0 += 32; gB1 += 32; gB2 += 32; gB3 += 32;
    __syncthreads();

    const int nk = K >> 5;
    for (int kt = 0; kt < nk; ++kt) {
        const int cur = kt & 1;
        if (kt + 1 < nk) {
            if (wv < 2) gload16x<2>(gA, &As[cur ^ 1][wv * 2][0][0]);  // NT
            gload16(gB0, &Bs[cur ^ 1][wv][0][0]);
            gload16(gB1, &Bs[cur ^ 1][wv][64][0]);
            gload16(gB2, &Bs[cur ^ 1][wv][128][0]);
            gload16(gB3, &Bs[cur ^ 1][wv][192][0]);
            gA += 32; gB0 += 32; gB1 += 32; gB2 += 32; gB3 += 32;
        }
        short8v av[2], bv[4];
        #pragma unroll
        for (int m = 0; m < 2; ++m)
            av[m] = *(const short8v*)&As[cur][kb][m * 16 + lr][0];
        #pragma unroll
        for (int n = 0; n < 4; ++n)
            bv[n] = *(const short8v*)&Bs[cur][kb][wv * 64 + n * 16 + lr][0];
        #pragma unroll
        for (int m = 0; m < 2; ++m)
            #pragma unroll
            for (int n = 0; n < 4; ++n)
                acc[m][n] = __builtin_amdgcn_mfma_f32_16x16x32_bf16(
                    av[m], bv[n], acc[m][n], 0, 0, 0);
        __syncthreads();
    }

    // bias + bf16 residual into acc
    #pragma unroll
    for (int n = 0; n < 4; ++n) {
        const int col = wv * 64 + n * 16 + lr;
        const float bcol = bias[col];
        #pragma unroll
        for (int m = 0; m < 2; ++m) {
            #pragma unroll
            for (int r = 0; r < 4; ++r) {
                const int grow = m0 + m * 16 + lh * 4 + r;
                acc[m][n][r] += bcol + bf2f(R[(long)grow * 256 + col]);
            }
        }
    }
    // per-row stats: sum over n, 16 lr lanes, then 4 waves via LDS
    #pragma unroll
    for (int m = 0; m < 2; ++m) {
        #pragma unroll
        for (int r = 0; r < 4; ++r) {
            float s = acc[m][0][r] + acc[m][1][r] + acc[m][2][r] + acc[m][3][r];
            float q = acc[m][0][r] * acc[m][0][r] + acc[m][1][r] * acc[m][1][r]
                    + acc[m][2][r] * acc[m][2][r] + acc[m][3][r] * acc[m][3][r];
            #pragma unroll
            for (int o = 1; o < 16; o <<= 1) {
                s += __shfl_xor(s, o);
                q += __shfl_xor(q, o);
            }
            if (lr == 0) {
                red[m * 16 + lh * 4 + r][wv][0] = s;
                red[m * 16 + lh * 4 + r][wv][1] = q;
            }
        }
    }
    __syncthreads();
    if (t < 32) {
        const float s = red[t][0][0] + red[t][1][0] + red[t][2][0] + red[t][3][0];
        const float q = red[t][0][1] + red[t][1][1] + red[t][2][1] + red[t][3][1];
        const float mean = s * (1.f / 256.f);
        smean[t] = mean;
        sinv[t] = rsqrtf(q * (1.f / 256.f) - mean * mean + 1e-5f);
    }
    __syncthreads();
    #pragma unroll
    for (int n = 0; n < 4; ++n) {
        const int col = wv * 64 + n * 16 + lr;
        const float gc = lg[col], bc = lb[col];
        #pragma unroll
        for (int m = 0; m < 2; ++m) {
            #pragma unroll
            for (int r = 0; r < 4; ++r) {
                const int row = m * 16 + lh * 4 + r;
                const int grow = m0 + row;
                const float y = (acc[m][n][r] - smean[row]) * sinv[row] * gc + bc;
                const long o = (long)grow * 256 + col;
                outh[o] = f2bf(y);
                if (outf) outf[o] = y;
                if (qout) {
                    const int qrow = grow - (grow >= LQT ? LQT : 0);
                    qout[o] = f2bf(y + pos[(long)qrow * 256 + col]);
                }
            }
        }
    }
}

// ---------------------------------------------------------------------------
// transpose (C, Ml) f32 -> (Ml, C) bf16, batch via blockIdx.z
// ---------------------------------------------------------------------------
__global__ __launch_bounds__(256)
void tp_k(const float* __restrict__ x, unsigned short* __restrict__ xt,
          int C, int Ml)
{
    __shared__ float tile[32][33];
    const int m0 = blockIdx.x * 32, c0 = blockIdx.y * 32;
    const int zb = blockIdx.z;
    const float* px = x + (long)zb * C * Ml;
    unsigned short* pxt = xt + (long)zb * Ml * C;
    const int t = threadIdx.x;
    {
        const int cl = t >> 3, m4 = (t & 7) * 4;
        const int gm = m0 + m4;
        if (gm < Ml) {
            const float4 v = *(const float4*)(px + (long)(c0 + cl) * Ml + gm);
            tile[cl][m4 + 0] = v.x; tile[cl][m4 + 1] = v.y;
            tile[cl][m4 + 2] = v.z; tile[cl][m4 + 3] = v.w;
        }
    }
    __syncthreads();
    {
        const int ml = t >> 3, c4 = (t & 7) * 4;
        const int gm = m0 + ml;
        if (gm < Ml) {
            ushort4 o;
            o.x = f2bf(tile[c4 + 0][ml]);
            o.y = f2bf(tile[c4 + 1][ml]);
            o.z = f2bf(tile[c4 + 2][ml]);
            o.w = f2bf(tile[c4 + 3][ml]);
            *(ushort4*)(pxt + (long)gm * C + c0 + c4) = o;
        }
    }
}

// ---------------------------------------------------------------------------
// GroupNorm 3-phase
// ---------------------------------------------------------------------------
__global__ __launch_bounds__(256)
void gn_part(const float* __restrict__ src, float* __restrict__ part)
{
    const int x = blockIdx.x;
    const int b = x >> 7, c = x & 127;
    int lvl, chunk;
    if (c < 96)       { lvl = 0; chunk = c; }
    else if (c < 120) { lvl = 1; chunk = c - 96; }
    else if (c < 126) { lvl = 2; chunk = c - 120; }
    else              { lvl = 3; chunk = c - 126; }
    const int starts[4] = {0, 9216, 11520, 12096};
    const int crows[4]  = {96, 96, 96, 72};
    const int rows = crows[lvl];
    const long base = ((long)b * LQT + starts[lvl] + (long)chunk * rows) * DD;
    const int t = threadIdx.x;
    float s = 0.f, sq = 0.f;
    for (int r = 0; r < rows; ++r) {
        const float v = src[base + (long)r * DD + t];
        s += v; sq += v * v;
    }
    #pragma unroll
    for (int o = 1; o < 8; o <<= 1) {
        s  += __shfl_xor(s, o);
        sq += __shfl_xor(sq, o);
    }
    if ((t & 7) == 0) {
        float* p = part + ((long)x * 32 + (t >> 3)) * 2;
        p[0] = s; p[1] = sq;
    }
}

__global__ void gn_fin(const float* __restrict__ part, float* __restrict__ stat)
{
    const int t = threadIdx.x;
    const int b = t >> 7, rest = t & 127;
    const int lvl = rest >> 5, grp = rest & 31;
    const int cbase[4] = {0, 96, 120, 126};
    const int ccnt[4]  = {96, 24, 6, 2};
    const int Ml[4]    = {9216, 2304, 576, 144};
    float s = 0.f, sq = 0.f;
    for (int i = 0; i < ccnt[lvl]; ++i) {
        const float* p = part + ((long)(b * 128 + cbase[lvl] + i) * 32 + grp) * 2;
        s += p[0]; sq += p[1];
    }
    const float cnt = (float)(Ml[lvl] * 8);
    const float mean = s / cnt;
    const float inv = rsqrtf(sq / cnt - mean * mean + 1e-5f);
    float* o = stat + ((b * 4 + lvl) * 32 + grp) * 2;
    o[0] = mean; o[1] = inv;
}

__global__ __launch_bounds__(256)
void gn_apply(const float* __restrict__ src, unsigned short* __restrict__ srch,
              unsigned short* __restrict__ qout,
              const float* __restrict__ stat,
              const float* __restrict__ gg, const float* __restrict__ gb,
              const float* __restrict__ pos)
{
    const int t = threadIdx.x;
    const long row = (long)blockIdx.x * 4 + (t >> 6);
    const int lane = t & 63;
    const int b = row >= LQT;
    const int q = (int)row - b * LQT;
    int lvl, start, S;
    level_of(q, lvl, start, S);
    const float2 ms = *(const float2*)(stat + ((b * 4 + lvl) * 32 + (lane >> 1)) * 2);
    const int col = lane * 4;
    const float4 v  = *(const float4*)(src + row * DD + col);
    const float4 gv = *(const float4*)(gg + lvl * DD + col);
    const float4 bv = *(const float4*)(gb + lvl * DD + col);
    float4 y;
    y.x = (v.x - ms.x) * ms.y * gv.x + bv.x;
    y.y = (v.y - ms.x) * ms.y * gv.y + bv.y;
    y.z = (v.z - ms.x) * ms.y * gv.z + bv.z;
    y.w = (v.w - ms.x) * ms.y * gv.w + bv.w;
    ushort4 hh;
    hh.x = f2bf(y.x); hh.y = f2bf(y.y); hh.z = f2bf(y.z); hh.w = f2bf(y.w);
    *(ushort4*)(srch + row * DD + col) = hh;
    const float4 pv = *(const float4*)(pos + (long)q * DD + col);
    ushort4 qq;
    qq.x = f2bf(y.x + pv.x); qq.y = f2bf(y.y + pv.y);
    qq.z = f2bf(y.z + pv.z); qq.w = f2bf(y.w + pv.w);
    *(ushort4*)(qout + row * DD + col) = qq;
}

__global__ __launch_bounds__(256)
void pos_k(float* __restrict__ pos, const float* __restrict__ lemb)
{
    const int q = blockIdx.x;
    const int d = threadIdx.x;
    int lvl, start, S;
    level_of(q, lvl, start, S);
    const int qi = q - start;
    const int r = qi / S, c = qi % S;
    const float twopi = 6.283185307179586f;
    float e; int dd;
    if (d < 128) { e = (float)(r + 1) / ((float)S + 1e-6f) * twopi; dd = d; }
    else         { e = (float)(c + 1) / ((float)S + 1e-6f) * twopi; dd = d - 128; }
    const float dimt = expf(9.210340371976184f * (float)(dd & ~1) / 128.f);
    const float p = e / dimt;
    const float v = (dd & 1) ? cosf(p) : sinf(p);
    pos[(long)q * DD + d] = v + lemb[lvl * DD + d];
}

// ---------------------------------------------------------------------------
// Deformable attention: XCD-chunked block swizzle for L2 gather locality.
// ---------------------------------------------------------------------------
__global__ __launch_bounds__(256)
void msdeform_k(const unsigned short* __restrict__ val,
                const unsigned short* __restrict__ off,
                const float* __restrict__ aw,
                unsigned short* __restrict__ out)
{
    __shared__ int   s_base[2][128][5];
    __shared__ float s_w[2][128][5];
    const int t = threadIdx.x;
    const int j = t >> 7;
    const int tt = t & 127;
    const int bid = blockIdx.x;
    const int sb = (bid & 7) * 1530 + (bid >> 3);
    const int bq = sb * 2 + j;
    const int b = bq >= LQT;
    const int q = bq - b * LQT;
    int lvl0, start0, S0;
    level_of(q, lvl0, start0, S0);
    const int qi = q - start0;
    {
        const int lv = (tt >> 2) & 3;
        const int SL[4]  = {96, 48, 24, 12};
        const int STL[4] = {0, 9216, 11520, 12096};
        const int S = SL[lv];
        const float refx = ((float)(qi % S0) + 0.5f) / (float)S0;
        const float refy = ((float)(qi / S0) + 0.5f) / (float)S0;
        const unsigned int ou = *(const unsigned int*)(off + (long)bq * 256 + 2 * tt);
        const float x = refx * (float)S - 0.5f + bf2f((unsigned short)(ou & 0xffffu));
        const float y = refy * (float)S - 0.5f + bf2f((unsigned short)(ou >> 16));
        const float logit = aw[(long)bq * 128 + tt];
        float mx = logit;
        #pragma unroll
        for (int s_ = 1; s_ < 16; s_ <<= 1) mx = fmaxf(mx, __shfl_xor(mx, s_));
        const float e = __expf(logit - mx);
        float sum = e;
        #pragma unroll
        for (int s_ = 1; s_ < 16; s_ <<= 1) sum += __shfl_xor(sum, s_);
        const float wat = e / sum;
        const float x0 = floorf(x), y0 = floorf(y);
        const float tx = x - x0, ty = y - y0;
        const int ix = (int)x0, iy = (int)y0;
        #pragma unroll
        for (int c = 0; c < 4; ++c) {
            const int dx = c & 1, dy = c >> 1;
            const int xi = ix + dx, yi = iy + dy;
            const bool ok = (xi >= 0) && (xi < S) && (yi >= 0) && (yi < S);
            const int cx = min(max(xi, 0), S - 1);
            const int cy = min(max(yi, 0), S - 1);
            const float wxy = (dx ? tx : 1.f - tx) * (dy ? ty : 1.f - ty);
            s_base[j][tt][c] = (STL[lv] + cy * S + cx) * 256;
            s_w[j][tt][c] = ok ? wxy * wat : 0.f;
        }
    }
    __syncthreads();
    const int h = tt >> 4, d8 = (tt >> 2) & 3, sub = tt & 3;
    const unsigned short* vb = val + (long)b * (LQT * DD) + h * 32 + d8 * 8;
    float a0 = 0.f, a1 = 0.f, a2 = 0.f, a3 = 0.f;
    float a4 = 0.f, a5 = 0.f, a6 = 0.f, a7 = 0.f;
    #pragma unroll
    for (int i = 0; i < 4; ++i) {
        const int task = h * 16 + i * 4 + sub;
        #pragma unroll
        for (int c = 0; c < 4; ++c) {
            const float wv = s_w[j][task][c];
            const uint4 g = *(const uint4*)(vb + s_base[j][task][c]);
            a0 = fmaf(wv, bf2f((unsigned short)(g.x & 0xffffu)), a0);
            a1 = fmaf(wv, bf2f((unsigned short)(g.x >> 16)), a1);
            a2 = fmaf(wv, bf2f((unsigned short)(g.y & 0xffffu)), a2);
            a3 = fmaf(wv, bf2f((unsigned short)(g.y >> 16)), a3);
            a4 = fmaf(wv, bf2f((unsigned short)(g.z & 0xffffu)), a4);
            a5 = fmaf(wv, bf2f((unsigned short)(g.z >> 16)), a5);
            a6 = fmaf(wv, bf2f((unsigned short)(g.w & 0xffffu)), a6);
            a7 = fmaf(wv, bf2f((unsigned short)(g.w >> 16)), a7);
        }
    }
    #pragma unroll
    for (int o = 1; o < 4; o <<= 1) {
        a0 += __shfl_xor(a0, o); a1 += __shfl_xor(a1, o);
        a2 += __shfl_xor(a2, o); a3 += __shfl_xor(a3, o);
        a4 += __shfl_xor(a4, o); a5 += __shfl_xor(a5, o);
        a6 += __shfl_xor(a6, o); a7 += __shfl_xor(a7, o);
    }
    if (sub == 0) {
        uint4 o;
        o.x = (unsigned)f2bf(a0) | ((unsigned)f2bf(a1) << 16);
        o.y = (unsigned)f2bf(a2) | ((unsigned)f2bf(a3) << 16);
        o.z = (unsigned)f2bf(a4) | ((unsigned)f2bf(a5) << 16);
        o.w = (unsigned)f2bf(a6) | ((unsigned)f2bf(a7) << 16);
        *(uint4*)(out + (long)bq * DD + h * 32 + d8 * 8) = o;
    }
}

// Fused conversion of ALL weights (10 segments, contiguous dst)
#define WCVT_TOTAL 5177344L
__global__ __launch_bounds__(256)
void wcvt_k(const float* __restrict__ s0, const float* __restrict__ s1,
            const float* __restrict__ s2, const float* __restrict__ s3,
            const float* __restrict__ s4, const float* __restrict__ s5,
            const float* __restrict__ s6, const float* __restrict__ s7,
            const float* __restrict__ s8, const float* __restrict__ s9,
            unsigned short* __restrict__ dst)
{
    const long i = ((long)blockIdx.x * 256 + threadIdx.x) * 4;
    if (i >= WCVT_TOTAL) return;
    const float* sp; long base;
    if (i < 1048576) {
        if (i < 655360) {
            if (i < 65536)       { sp = s0; base = 0; }
            else if (i < 196608) { sp = s1; base = 65536; }
            else if (i < 393216) { sp = s2; base = 196608; }
            else                 { sp = s3; base = 393216; }
        } else                   { sp = s4; base = 655360; }
    } else if (i < 2031616) {
        if (i < 1245184)         { sp = s5; base = 1048576; }
        else if (i < 1638400)    { sp = s6; base = 1245184; }
        else                     { sp = s7; base = 1638400; }
    } else if (i < 3604480)      { sp = s8; base = 2031616; }
    else                         { sp = s9; base = 3604480; }
    const float4 v = *(const float4*)(sp + (i - base));
    ushort4 o;
    o.x = f2bf(v.x); o.y = f2bf(v.y); o.z = f2bf(v.z); o.w = f2bf(v.w);
    *(ushort4*)(dst + i) = o;
}

__global__ void tail_k(float* __restrict__ o)
{
    const float tv[28] = {0.f, 9216.f, 11520.f, 12096.f,
                          96.f, 96.f, 48.f, 48.f, 24.f, 24.f, 12.f, 12.f,
                          1.f, 1.f, 1.f, 1.f, 1.f, 1.f, 1.f, 1.f,
                          1.f, 1.f, 1.f, 1.f, 1.f, 1.f, 1.f, 1.f};
    const int t = threadIdx.x;
    if (t < 28) o[t] = tv[t];
}

extern "C" void kernel_launch(void* const* d_in, const int* in_sizes, int n_in,
                              void* d_out, int out_size, void* d_ws, size_t ws_size,
                              hipStream_t stream)
{
    const float* xs[4]  = {(const float*)d_in[0], (const float*)d_in[3],
                           (const float*)d_in[6], (const float*)d_in[9]};
    const float* fcw[4] = {(const float*)d_in[1], (const float*)d_in[4],
                           (const float*)d_in[7], (const float*)d_in[10]};
    const float* fcb[4] = {(const float*)d_in[2], (const float*)d_in[5],
                           (const float*)d_in[8], (const float*)d_in[11]};
    const float* gn_g = (const float*)d_in[12];
    const float* gn_b = (const float*)d_in[13];
    const float* lemb = (const float*)d_in[14];
    const float* off_w = (const float*)d_in[15];
    const float* off_b = (const float*)d_in[16];
    const float* aw_w  = (const float*)d_in[17];
    const float* aw_b  = (const float*)d_in[18];
    const float* val_w = (const float*)d_in[19];
    const float* val_b = (const float*)d_in[20];
    const float* out_w = (const float*)d_in[21];
    const float* out_b = (const float*)d_in[22];
    const float* ln1_g = (const float*)d_in[23];
    const float* ln1_b = (const float*)d_in[24];
    const float* l1_w  = (const float*)d_in[25];
    const float* l1_b  = (const float*)d_in[26];
    const float* l2_w  = (const float*)d_in[27];
    const float* l2_b  = (const float*)d_in[28];
    const float* ln2_g = (const float*)d_in[29];
    const float* ln2_b = (const float*)d_in[30];

    float* src = (float*)d_out;                 // (B, LQ, D) final f32 out
    float* ws = (float*)d_ws;
    float* pos = ws;                            // 3,133,440 f32
    float* awb = pos + 3133440;                 // 3,133,440 f32 (aw logits)
    unsigned short* bigbuf = (unsigned short*)(awb + 3133440);
    unsigned short* xt     = bigbuf;            // setup only
    unsigned short* off_bf = bigbuf;
    unsigned short* val_bf = bigbuf + 6266880;
    unsigned short* msd_bf = bigbuf + 12533760;
    unsigned short* hid_bf = bigbuf;            // FFN hidden overlays all
    unsigned short* q_bf   = bigbuf + 25067520;
    unsigned short* src_bf = q_bf + 6266880;
    unsigned short* wb     = src_bf + 6266880;
    unsigned short* wb_fc[4];
    wb_fc[0] = wb;
    wb_fc[1] = wb_fc[0] + 65536;
    wb_fc[2] = wb_fc[1] + 131072;
    wb_fc[3] = wb_fc[2] + 196608;
    unsigned short* wb_off = wb_fc[3] + 262144;
    unsigned short* wb_aw  = wb_off + 393216;
    unsigned short* wb_val = wb_aw  + 196608;
    unsigned short* wb_out = wb_val + 393216;
    unsigned short* wb_l1  = wb_out + 393216;
    unsigned short* wb_l2  = wb_l1  + 1572864;
    float* part = (float*)(wb_l2 + 1572864);    // 16384 f32
    float* stat = part + 16384;                 // 512 f32
    (void)in_sizes; (void)n_in; (void)out_size; (void)ws_size;

    const int CINS[4]   = {256, 512, 768, 1024};
    const int SS[4]     = {96, 48, 24, 12};
    const int STARTS[4] = {0, 9216, 11520, 12096};
    const long XTOFF[4] = {0, 4718592, 7077888, 7962624};

    // 0) positional embedding + all weights -> bf16 (one kernel)
    pos_k<<<LQT, 256, 0, stream>>>(pos, lemb);
    wcvt_k<<<(WCVT_TOTAL / 4 + 255) / 256, 256, 0, stream>>>(
        fcw[0], fcw[1], fcw[2], fcw[3], off_w, aw_w, val_w, out_w, l1_w, l2_w, wb);

    // 1) transpose inputs + bf16 projections (f32 out into src)
    for (int i = 0; i < 4; ++i) {
        const int Ml = SS[i] * SS[i];
        tp_k<<<dim3((Ml + 31) / 32, CINS[i] / 32, BB), 256, 0, stream>>>(
            xs[i], xt + XTOFF[i], CINS[i], Ml);
    }
    for (int i = 0; i < 4; ++i) {
        const int Ml = SS[i] * SS[i];
        gemm64<<<dim3((Ml + 63) / 64, 2, BB), 256, 0, stream>>>(
            xt + XTOFF[i], (long)Ml * CINS[i],
            wb_fc[i], fcb[i],
            src + (long)STARTS[i] * DD, (long)LQT * DD,
            Ml, DD, CINS[i]);
    }
    // 2) group norm (3-phase) -> src_bf + q_bf
    gn_part<<<256, 256, 0, stream>>>(src, part);
    gn_fin<<<1, 256, 0, stream>>>(part, stat);
    gn_apply<<<MROWS / 4, 256, 0, stream>>>(src, src_bf, q_bf, stat, gn_g, gn_b, pos);

    // 3) encoder layers
    for (int l = 0; l < 6; ++l) {
        gemm_qkv<<<dim3(383, 5), 256, 0, stream>>>(
            q_bf, src_bf,
            wb_off + (long)l * 65536, wb_aw + (long)l * 32768,
            wb_val + (long)l * 65536,
            off_b + l * DD, aw_b + l * 128, val_b + l * DD,
            awb, off_bf, val_bf);
        msdeform_k<<<MROWS / 2, 256, 0, stream>>>(val_bf, off_bf, awb, msd_bf);
        // out-proj + bf16 residual + LN1 -> src_bf  (A = msd, NT stream)
        gemm_ln<<<765, 256, 0, stream>>>(
            msd_bf, wb_out + (long)l * 65536, out_b + l * DD, src_bf,
            ln1_g + l * DD, ln1_b + l * DD, nullptr, src_bf,
            nullptr, nullptr, MROWS, DD);
        gemm128<<<dim3(192, 8), 256, 0, stream>>>(
            src_bf, wb_l1 + (long)l * 262144, l1_b + l * DFFN, hid_bf,
            MROWS, DFFN, DD);
        // ffn2 + bf16 residual + LN2 (+ next q)  (A = hid, NT stream)
        const bool last = (l == 5);
        gemm_ln<<<765, 256, 0, stream>>>(
            hid_bf, wb_l2 + (long)l * 262144, l2_b + l * DD, src_bf,
            ln2_g + l * DD, ln2_b + l * DD, last ? src : nullptr, src_bf,
            last ? nullptr : pos, last ? nullptr : q_bf, MROWS, DFFN);
    }
    // 4) constant tail outputs
    tail_k<<<1, 32, 0, stream>>>(src + (long)BB * LQT * DD);
}

// Round 14
// 1676.850 us; speedup vs baseline: 1.1252x; 1.1252x over previous
//
#include <hip/hip_runtime.h>
#include <math.h>

#define DD 256
#define DFFN 1024
#define LQT 12240
#define BB 2
#define MROWS (BB * LQT)   // 24480

typedef __attribute__((ext_vector_type(8))) short short8v;
typedef __attribute__((ext_vector_type(4))) float floatx4;

__device__ __forceinline__ unsigned short f2bf(float x) {
    unsigned int u = __builtin_bit_cast(unsigned int, x);
    u = (u + 0x7fffu + ((u >> 16) & 1u)) >> 16;
    return (unsigned short)u;
}
__device__ __forceinline__ float bf2f(unsigned short h) {
    unsigned int u = ((unsigned int)h) << 16;
    return __builtin_bit_cast(float, u);
}

__device__ __forceinline__ void gload16(const unsigned short* g, unsigned short* lds) {
    __builtin_amdgcn_global_load_lds(
        (const __attribute__((address_space(1))) unsigned int*)g,
        (__attribute__((address_space(3))) unsigned int*)lds, 16, 0, 0);
}

__device__ __forceinline__ void level_of(int q, int& lvl, int& start, int& S) {
    if (q < 9216)       { lvl = 0; start = 0;     S = 96; }
    else if (q < 11520) { lvl = 1; start = 9216;  S = 48; }
    else if (q < 12096) { lvl = 2; start = 11520; S = 24; }
    else                { lvl = 3; start = 12096; S = 12; }
}

// ---------------------------------------------------------------------------
// Merged QKV projection: grid (383, 5), 256t. BK=64 (4 K-steps), 2-phase.
// LDS 48KB static. Per wave per step: 2 A + 4 B gload16.
// ---------------------------------------------------------------------------
__global__ __launch_bounds__(256)
void gemm_qkv(const unsigned short* __restrict__ Aq,
              const unsigned short* __restrict__ Asr,
              const unsigned short* __restrict__ Woff,
              const unsigned short* __restrict__ Waw,
              const unsigned short* __restrict__ Wval,
              const float* __restrict__ boff, const float* __restrict__ baw,
              const float* __restrict__ bval,
              float* __restrict__ awbo, unsigned short* __restrict__ offo,
              unsigned short* __restrict__ valo)
{
    __shared__ alignas(16) unsigned short As[2][8][64][8];
    __shared__ alignas(16) unsigned short Bs[2][8][128][8];
    const int t = threadIdx.x;
    const int m0 = blockIdx.x * 64;
    const int y = blockIdx.y;
    const unsigned short* A; const unsigned short* Wb; const float* bi;
    int nb, mode;
    if (y < 3) {
        A = Aq;
        if (y < 2) { Wb = Woff; bi = boff; nb = y * 128; mode = 0; }
        else       { Wb = Waw;  bi = baw;  nb = 0;       mode = 1; }
    } else {
        A = Asr; Wb = Wval; bi = bval; nb = (y - 3) * 128; mode = 2;
    }
    const int wv = __builtin_amdgcn_readfirstlane(t >> 6);
    const int lane = t & 63;
    const int wm = wv >> 1, wn = wv & 1;
    const int kb = lane >> 4, lr = lane & 15;

    const int ar = min(m0 + lane, MROWS - 1);
    const unsigned short* gA = A + (long)ar * 256;

    floatx4 acc[2][4];
    #pragma unroll
    for (int m = 0; m < 2; ++m)
        #pragma unroll
        for (int n = 0; n < 4; ++n)
            acc[m][n] = (floatx4){0.f, 0.f, 0.f, 0.f};

    // stage(buf, kt): A chunks {2wv,2wv+1}; B (ks in {2wv,2wv+1}) x half {0,1}
    #define QKV_STAGE(buf, kt) do {                                          \
        const int ko_ = (kt) * 64;                                           \
        gload16(gA + ko_ + (2 * wv) * 8,     &As[buf][2 * wv][0][0]);        \
        gload16(gA + ko_ + (2 * wv + 1) * 8, &As[buf][2 * wv + 1][0][0]);    \
        _Pragma("unroll")                                                    \
        for (int j_ = 0; j_ < 2; ++j_) {                                     \
            const int ks_ = 2 * wv + j_;                                     \
            _Pragma("unroll")                                                \
            for (int h_ = 0; h_ < 2; ++h_)                                   \
                gload16(Wb + (long)(nb + h_ * 64 + lane) * 256 + ko_ + ks_ * 8, \
                        &Bs[buf][ks_][h_ * 64][0]);                          \
        }                                                                    \
    } while (0)

    QKV_STAGE(0, 0);
    __syncthreads();

    #pragma unroll
    for (int kt = 0; kt < 4; ++kt) {
        const int cur = kt & 1;
        if (kt < 3) QKV_STAGE(cur ^ 1, kt + 1);
        #pragma unroll
        for (int hf = 0; hf < 2; ++hf) {
            const int kbb = hf * 4 + kb;
            short8v av[2], bv[4];
            #pragma unroll
            for (int m = 0; m < 2; ++m)
                av[m] = *(const short8v*)&As[cur][kbb][wm * 32 + m * 16 + lr][0];
            #pragma unroll
            for (int n = 0; n < 4; ++n)
                bv[n] = *(const short8v*)&Bs[cur][kbb][wn * 64 + n * 16 + lr][0];
            #pragma unroll
            for (int m = 0; m < 2; ++m)
                #pragma unroll
                for (int n = 0; n < 4; ++n)
                    acc[m][n] = __builtin_amdgcn_mfma_f32_16x16x32_bf16(
                        av[m], bv[n], acc[m][n], 0, 0, 0);
        }
        __syncthreads();
    }
    #undef QKV_STAGE

    const int lh = lane >> 4;
    #pragma unroll
    for (int m = 0; m < 2; ++m) {
        const int row0 = m0 + wm * 32 + m * 16 + lh * 4;
        #pragma unroll
        for (int n = 0; n < 4; ++n) {
            const int col = nb + wn * 64 + n * 16 + lr;
            const float b = bi[col];
            #pragma unroll
            for (int r = 0; r < 4; ++r) {
                const int row = row0 + r;
                if (row >= MROWS) continue;
                const float v = acc[m][n][r] + b;
                if (mode == 0)      offo[(long)row * 256 + col] = f2bf(v);
                else if (mode == 1) awbo[(long)row * 128 + col] = v;
                else                valo[(long)row * 256 + col] = f2bf(v);
            }
        }
    }
}

// ---------------------------------------------------------------------------
// BM=64 x BN=128 bf16 GEMM (input projections only, setup), 2-phase BK=32
// ---------------------------------------------------------------------------
__global__ __launch_bounds__(256)
void gemm64(const unsigned short* __restrict__ A, long aZ,
            const unsigned short* __restrict__ W,
            const float* __restrict__ bias,
            float* __restrict__ Cf, long cZ,
            int M, int N, int K)
{
    __shared__ alignas(16) unsigned short As[2][4][64][8];
    __shared__ alignas(16) unsigned short Bs[2][4][128][8];
    const int t = threadIdx.x;
    const int z = blockIdx.z;
    A  += (long)z * aZ;
    Cf += (long)z * cZ;
    const int m0 = blockIdx.x * 64;
    const int n0 = blockIdx.y * 128;
    const int wv = __builtin_amdgcn_readfirstlane(t >> 6);
    const int lane = t & 63;
    const int wm = wv >> 1, wn = wv & 1;
    const int kb = lane >> 4, lr = lane & 15;

    const int ar = min(m0 + lane, M - 1);
    const unsigned short* gA  = A + (long)ar * K + wv * 8;
    const unsigned short* gB0 = W + (long)(n0 + lane) * K + wv * 8;
    const unsigned short* gB1 = W + (long)(n0 + 64 + lane) * K + wv * 8;

    floatx4 acc[2][4];
    #pragma unroll
    for (int m = 0; m < 2; ++m)
        #pragma unroll
        for (int n = 0; n < 4; ++n)
            acc[m][n] = (floatx4){0.f, 0.f, 0.f, 0.f};

    gload16(gA,  &As[0][wv][0][0]);
    gload16(gB0, &Bs[0][wv][0][0]);
    gload16(gB1, &Bs[0][wv][64][0]);
    gA += 32; gB0 += 32; gB1 += 32;
    __syncthreads();

    const int nk = K >> 5;
    for (int kt = 0; kt < nk; ++kt) {
        const int cur = kt & 1;
        if (kt + 1 < nk) {
            gload16(gA,  &As[cur ^ 1][wv][0][0]);
            gload16(gB0, &Bs[cur ^ 1][wv][0][0]);
            gload16(gB1, &Bs[cur ^ 1][wv][64][0]);
            gA += 32; gB0 += 32; gB1 += 32;
        }
        short8v av[2], bv[4];
        #pragma unroll
        for (int m = 0; m < 2; ++m)
            av[m] = *(const short8v*)&As[cur][kb][wm * 32 + m * 16 + lr][0];
        #pragma unroll
        for (int n = 0; n < 4; ++n)
            bv[n] = *(const short8v*)&Bs[cur][kb][wn * 64 + n * 16 + lr][0];
        #pragma unroll
        for (int m = 0; m < 2; ++m)
            #pragma unroll
            for (int n = 0; n < 4; ++n)
                acc[m][n] = __builtin_amdgcn_mfma_f32_16x16x32_bf16(
                    av[m], bv[n], acc[m][n], 0, 0, 0);
        __syncthreads();
    }

    const int lh = lane >> 4;
    #pragma unroll
    for (int m = 0; m < 2; ++m) {
        const int row0 = m0 + wm * 32 + m * 16 + lh * 4;
        #pragma unroll
        for (int n = 0; n < 4; ++n) {
            const int col = n0 + wn * 64 + n * 16 + lr;
            const float b = bias[col];
            #pragma unroll
            for (int r = 0; r < 4; ++r) {
                const int row = row0 + r;
                if (row >= M) continue;
                Cf[(long)row * N + col] = acc[m][n][r] + b;
            }
        }
    }
}

// ---------------------------------------------------------------------------
// FFN1 BM=128 x BN=128 (relu -> bf16), 2-phase BK=32 (8 steps) — unchanged
// ---------------------------------------------------------------------------
__global__ __launch_bounds__(256)
void gemm128(const unsigned short* __restrict__ A,
             const unsigned short* __restrict__ W,
             const float* __restrict__ bias, unsigned short* __restrict__ Ch,
             int M, int N, int K)
{
    __shared__ alignas(16) unsigned short As[2][4][128][8];
    __shared__ alignas(16) unsigned short Bs[2][4][128][8];
    const int t = threadIdx.x;
    const int m0 = blockIdx.x * 128;
    const int n0 = blockIdx.y * 128;
    const int wv = __builtin_amdgcn_readfirstlane(t >> 6);
    const int lane = t & 63;
    const int wm = wv >> 1, wn = wv & 1;
    const int kb = lane >> 4, lr = lane & 15;

    const int r0 = min(m0 + lane, M - 1);
    const int r1 = min(m0 + 64 + lane, M - 1);
    const unsigned short* gA0 = A + (long)r0 * K + wv * 8;
    const unsigned short* gA1 = A + (long)r1 * K + wv * 8;
    const unsigned short* gB0 = W + (long)(n0 + lane) * K + wv * 8;
    const unsigned short* gB1 = W + (long)(n0 + 64 + lane) * K + wv * 8;

    floatx4 acc[4][4];
    #pragma unroll
    for (int m = 0; m < 4; ++m)
        #pragma unroll
        for (int n = 0; n < 4; ++n)
            acc[m][n] = (floatx4){0.f, 0.f, 0.f, 0.f};

    gload16(gA0, &As[0][wv][0][0]);
    gload16(gA1, &As[0][wv][64][0]);
    gload16(gB0, &Bs[0][wv][0][0]);
    gload16(gB1, &Bs[0][wv][64][0]);
    gA0 += 32; gA1 += 32; gB0 += 32; gB1 += 32;
    __syncthreads();

    const int nk = K >> 5;
    for (int kt = 0; kt < nk; ++kt) {
        const int cur = kt & 1;
        if (kt + 1 < nk) {
            gload16(gA0, &As[cur ^ 1][wv][0][0]);
            gload16(gA1, &As[cur ^ 1][wv][64][0]);
            gload16(gB0, &Bs[cur ^ 1][wv][0][0]);
            gload16(gB1, &Bs[cur ^ 1][wv][64][0]);
            gA0 += 32; gA1 += 32; gB0 += 32; gB1 += 32;
        }
        short8v av[4], bv[4];
        #pragma unroll
        for (int m = 0; m < 4; ++m)
            av[m] = *(const short8v*)&As[cur][kb][wm * 64 + m * 16 + lr][0];
        #pragma unroll
        for (int n = 0; n < 4; ++n)
            bv[n] = *(const short8v*)&Bs[cur][kb][wn * 64 + n * 16 + lr][0];
        #pragma unroll
        for (int m = 0; m < 4; ++m)
            #pragma unroll
            for (int n = 0; n < 4; ++n)
                acc[m][n] = __builtin_amdgcn_mfma_f32_16x16x32_bf16(
                    av[m], bv[n], acc[m][n], 0, 0, 0);
        __syncthreads();
    }

    const int lh = lane >> 4;
    #pragma unroll
    for (int m = 0; m < 4; ++m) {
        const int row0 = m0 + wm * 64 + m * 16 + lh * 4;
        #pragma unroll
        for (int n = 0; n < 4; ++n) {
            const int col = n0 + wn * 64 + n * 16 + lr;
            const float b = bias[col];
            #pragma unroll
            for (int r = 0; r < 4; ++r) {
                const int row = row0 + r;
                if (row >= M) continue;
                Ch[(long)row * N + col] = f2bf(fmaxf(acc[m][n][r] + b, 0.f));
            }
        }
    }
}

// ---------------------------------------------------------------------------
// BM=32 x BN=256 GEMM + bias + bf16-residual + LayerNorm. BK=64:
// out-proj 4 steps, FFN2 16 steps. Dynamic LDS 75008 B (2 blocks/CU).
// Per wave per step: 1 A + 8 B gload16.
// ---------------------------------------------------------------------------
__global__ __launch_bounds__(256)
void gemm_ln(const unsigned short* __restrict__ A,
             const unsigned short* __restrict__ W,
             const float* __restrict__ bias, const unsigned short* R,
             const float* __restrict__ lg, const float* __restrict__ lb,
             float* outf, unsigned short* outh,
             const float* __restrict__ pos, unsigned short* __restrict__ qout,
             int M, int K)
{
    extern __shared__ __align__(16) unsigned short lds[];
    unsigned short* AsD = lds;            // [2][8][32][8]  = 4096 shorts
    unsigned short* BsD = lds + 4096;     // [2][8][256][8] = 32768 shorts
    float* red   = (float*)(lds + 36864); // [32][4][2]
    float* smean = red + 256;
    float* sinv  = smean + 32;

    const int t = threadIdx.x;
    const int m0 = blockIdx.x * 32;
    const int wv = __builtin_amdgcn_readfirstlane(t >> 6);
    const int lane = t & 63;
    const int kb = lane >> 4, lr = lane & 15;
    const int lh = kb;

    // A: wave wv stages slices {2wv, 2wv+1}; lane<32 -> slice 2wv row lane,
    // lane>=32 -> slice 2wv+1 row lane-32 (matches linear LDS fill).
    const unsigned short* gA = A + (long)(m0 + (lane & 31)) * K
                                 + (2 * wv + (lane >> 5)) * 8;

    floatx4 acc[2][4];
    #pragma unroll
    for (int m = 0; m < 2; ++m)
        #pragma unroll
        for (int n = 0; n < 4; ++n)
            acc[m][n] = (floatx4){0.f, 0.f, 0.f, 0.f};

    #define LN_STAGE(buf, kt) do {                                              \
        const long ko_ = (long)(kt) * 64;                                       \
        gload16(gA + ko_, AsD + (((buf) * 8 + 2 * wv) * 32) * 8);               \
        _Pragma("unroll")                                                       \
        for (int j_ = 0; j_ < 2; ++j_) {                                        \
            const int ks_ = 2 * wv + j_;                                        \
            _Pragma("unroll")                                                   \
            for (int h_ = 0; h_ < 4; ++h_)                                      \
                gload16(W + (long)(h_ * 64 + lane) * K + ko_ + ks_ * 8,         \
                        BsD + (((buf) * 8 + ks_) * 256 + h_ * 64) * 8);         \
        }                                                                       \
    } while (0)

    LN_STAGE(0, 0);
    __syncthreads();

    const int nk = K >> 6;
    for (int kt = 0; kt < nk; ++kt) {
        const int cur = kt & 1;
        if (kt + 1 < nk) LN_STAGE(cur ^ 1, kt + 1);
        #pragma unroll
        for (int hf = 0; hf < 2; ++hf) {
            const int kbb = hf * 4 + kb;
            short8v av[2], bv[4];
            #pragma unroll
            for (int m = 0; m < 2; ++m)
                av[m] = *(const short8v*)&AsD[((cur * 8 + kbb) * 32 + m * 16 + lr) * 8];
            #pragma unroll
            for (int n = 0; n < 4; ++n)
                bv[n] = *(const short8v*)&BsD[((cur * 8 + kbb) * 256 + wv * 64 + n * 16 + lr) * 8];
            #pragma unroll
            for (int m = 0; m < 2; ++m)
                #pragma unroll
                for (int n = 0; n < 4; ++n)
                    acc[m][n] = __builtin_amdgcn_mfma_f32_16x16x32_bf16(
                        av[m], bv[n], acc[m][n], 0, 0, 0);
        }
        __syncthreads();
    }
    #undef LN_STAGE

    // bias + bf16 residual into acc
    #pragma unroll
    for (int n = 0; n < 4; ++n) {
        const int col = wv * 64 + n * 16 + lr;
        const float bcol = bias[col];
        #pragma unroll
        for (int m = 0; m < 2; ++m) {
            #pragma unroll
            for (int r = 0; r < 4; ++r) {
                const int grow = m0 + m * 16 + lh * 4 + r;
                acc[m][n][r] += bcol + bf2f(R[(long)grow * 256 + col]);
            }
        }
    }
    // per-row stats: sum over n, 16 lr lanes, then 4 waves via LDS
    #pragma unroll
    for (int m = 0; m < 2; ++m) {
        #pragma unroll
        for (int r = 0; r < 4; ++r) {
            float s = acc[m][0][r] + acc[m][1][r] + acc[m][2][r] + acc[m][3][r];
            float q = acc[m][0][r] * acc[m][0][r] + acc[m][1][r] * acc[m][1][r]
                    + acc[m][2][r] * acc[m][2][r] + acc[m][3][r] * acc[m][3][r];
            #pragma unroll
            for (int o = 1; o < 16; o <<= 1) {
                s += __shfl_xor(s, o);
                q += __shfl_xor(q, o);
            }
            if (lr == 0) {
                red[(m * 16 + lh * 4 + r) * 8 + wv * 2 + 0] = s;
                red[(m * 16 + lh * 4 + r) * 8 + wv * 2 + 1] = q;
            }
        }
    }
    __syncthreads();
    if (t < 32) {
        const float s = red[t * 8 + 0] + red[t * 8 + 2] + red[t * 8 + 4] + red[t * 8 + 6];
        const float q = red[t * 8 + 1] + red[t * 8 + 3] + red[t * 8 + 5] + red[t * 8 + 7];
        const float mean = s * (1.f / 256.f);
        smean[t] = mean;
        sinv[t] = rsqrtf(q * (1.f / 256.f) - mean * mean + 1e-5f);
    }
    __syncthreads();
    #pragma unroll
    for (int n = 0; n < 4; ++n) {
        const int col = wv * 64 + n * 16 + lr;
        const float gc = lg[col], bc = lb[col];
        #pragma unroll
        for (int m = 0; m < 2; ++m) {
            #pragma unroll
            for (int r = 0; r < 4; ++r) {
                const int row = m * 16 + lh * 4 + r;
                const int grow = m0 + row;
                const float y = (acc[m][n][r] - smean[row]) * sinv[row] * gc + bc;
                const long o = (long)grow * 256 + col;
                outh[o] = f2bf(y);
                if (outf) outf[o] = y;
                if (qout) {
                    const int qrow = grow - (grow >= LQT ? LQT : 0);
                    qout[o] = f2bf(y + pos[(long)qrow * 256 + col]);
                }
            }
        }
    }
}

// ---------------------------------------------------------------------------
// transpose (C, Ml) f32 -> (Ml, C) bf16, batch via blockIdx.z
// ---------------------------------------------------------------------------
__global__ __launch_bounds__(256)
void tp_k(const float* __restrict__ x, unsigned short* __restrict__ xt,
          int C, int Ml)
{
    __shared__ float tile[32][33];
    const int m0 = blockIdx.x * 32, c0 = blockIdx.y * 32;
    const int zb = blockIdx.z;
    const float* px = x + (long)zb * C * Ml;
    unsigned short* pxt = xt + (long)zb * Ml * C;
    const int t = threadIdx.x;
    {
        const int cl = t >> 3, m4 = (t & 7) * 4;
        const int gm = m0 + m4;
        if (gm < Ml) {
            const float4 v = *(const float4*)(px + (long)(c0 + cl) * Ml + gm);
            tile[cl][m4 + 0] = v.x; tile[cl][m4 + 1] = v.y;
            tile[cl][m4 + 2] = v.z; tile[cl][m4 + 3] = v.w;
        }
    }
    __syncthreads();
    {
        const int ml = t >> 3, c4 = (t & 7) * 4;
        const int gm = m0 + ml;
        if (gm < Ml) {
            ushort4 o;
            o.x = f2bf(tile[c4 + 0][ml]);
            o.y = f2bf(tile[c4 + 1][ml]);
            o.z = f2bf(tile[c4 + 2][ml]);
            o.w = f2bf(tile[c4 + 3][ml]);
            *(ushort4*)(pxt + (long)gm * C + c0 + c4) = o;
        }
    }
}

// ---------------------------------------------------------------------------
// GroupNorm 3-phase
// ---------------------------------------------------------------------------
__global__ __launch_bounds__(256)
void gn_part(const float* __restrict__ src, float* __restrict__ part)
{
    const int x = blockIdx.x;
    const int b = x >> 7, c = x & 127;
    int lvl, chunk;
    if (c < 96)       { lvl = 0; chunk = c; }
    else if (c < 120) { lvl = 1; chunk = c - 96; }
    else if (c < 126) { lvl = 2; chunk = c - 120; }
    else              { lvl = 3; chunk = c - 126; }
    const int starts[4] = {0, 9216, 11520, 12096};
    const int crows[4]  = {96, 96, 96, 72};
    const int rows = crows[lvl];
    const long base = ((long)b * LQT + starts[lvl] + (long)chunk * rows) * DD;
    const int t = threadIdx.x;
    float s = 0.f, sq = 0.f;
    for (int r = 0; r < rows; ++r) {
        const float v = src[base + (long)r * DD + t];
        s += v; sq += v * v;
    }
    #pragma unroll
    for (int o = 1; o < 8; o <<= 1) {
        s  += __shfl_xor(s, o);
        sq += __shfl_xor(sq, o);
    }
    if ((t & 7) == 0) {
        float* p = part + ((long)x * 32 + (t >> 3)) * 2;
        p[0] = s; p[1] = sq;
    }
}

__global__ void gn_fin(const float* __restrict__ part, float* __restrict__ stat)
{
    const int t = threadIdx.x;
    const int b = t >> 7, rest = t & 127;
    const int lvl = rest >> 5, grp = rest & 31;
    const int cbase[4] = {0, 96, 120, 126};
    const int ccnt[4]  = {96, 24, 6, 2};
    const int Ml[4]    = {9216, 2304, 576, 144};
    float s = 0.f, sq = 0.f;
    for (int i = 0; i < ccnt[lvl]; ++i) {
        const float* p = part + ((long)(b * 128 + cbase[lvl] + i) * 32 + grp) * 2;
        s += p[0]; sq += p[1];
    }
    const float cnt = (float)(Ml[lvl] * 8);
    const float mean = s / cnt;
    const float inv = rsqrtf(sq / cnt - mean * mean + 1e-5f);
    float* o = stat + ((b * 4 + lvl) * 32 + grp) * 2;
    o[0] = mean; o[1] = inv;
}

__global__ __launch_bounds__(256)
void gn_apply(const float* __restrict__ src, unsigned short* __restrict__ srch,
              unsigned short* __restrict__ qout,
              const float* __restrict__ stat,
              const float* __restrict__ gg, const float* __restrict__ gb,
              const float* __restrict__ pos)
{
    const int t = threadIdx.x;
    const long row = (long)blockIdx.x * 4 + (t >> 6);
    const int lane = t & 63;
    const int b = row >= LQT;
    const int q = (int)row - b * LQT;
    int lvl, start, S;
    level_of(q, lvl, start, S);
    const float2 ms = *(const float2*)(stat + ((b * 4 + lvl) * 32 + (lane >> 1)) * 2);
    const int col = lane * 4;
    const float4 v  = *(const float4*)(src + row * DD + col);
    const float4 gv = *(const float4*)(gg + lvl * DD + col);
    const float4 bv = *(const float4*)(gb + lvl * DD + col);
    float4 y;
    y.x = (v.x - ms.x) * ms.y * gv.x + bv.x;
    y.y = (v.y - ms.x) * ms.y * gv.y + bv.y;
    y.z = (v.z - ms.x) * ms.y * gv.z + bv.z;
    y.w = (v.w - ms.x) * ms.y * gv.w + bv.w;
    ushort4 hh;
    hh.x = f2bf(y.x); hh.y = f2bf(y.y); hh.z = f2bf(y.z); hh.w = f2bf(y.w);
    *(ushort4*)(srch + row * DD + col) = hh;
    const float4 pv = *(const float4*)(pos + (long)q * DD + col);
    ushort4 qq;
    qq.x = f2bf(y.x + pv.x); qq.y = f2bf(y.y + pv.y);
    qq.z = f2bf(y.z + pv.z); qq.w = f2bf(y.w + pv.w);
    *(ushort4*)(qout + row * DD + col) = qq;
}

__global__ __launch_bounds__(256)
void pos_k(float* __restrict__ pos, const float* __restrict__ lemb)
{
    const int q = blockIdx.x;
    const int d = threadIdx.x;
    int lvl, start, S;
    level_of(q, lvl, start, S);
    const int qi = q - start;
    const int r = qi / S, c = qi % S;
    const float twopi = 6.283185307179586f;
    float e; int dd;
    if (d < 128) { e = (float)(r + 1) / ((float)S + 1e-6f) * twopi; dd = d; }
    else         { e = (float)(c + 1) / ((float)S + 1e-6f) * twopi; dd = d - 128; }
    const float dimt = expf(9.210340371976184f * (float)(dd & ~1) / 128.f);
    const float p = e / dimt;
    const float v = (dd & 1) ? cosf(p) : sinf(p);
    pos[(long)q * DD + d] = v + lemb[lvl * DD + d];
}

// ---------------------------------------------------------------------------
// Deformable attention: XCD-chunked block swizzle for L2 gather locality.
// ---------------------------------------------------------------------------
__global__ __launch_bounds__(256)
void msdeform_k(const unsigned short* __restrict__ val,
                const unsigned short* __restrict__ off,
                const float* __restrict__ aw,
                unsigned short* __restrict__ out)
{
    __shared__ int   s_base[2][128][5];
    __shared__ float s_w[2][128][5];
    const int t = threadIdx.x;
    const int j = t >> 7;
    const int tt = t & 127;
    const int bid = blockIdx.x;
    const int sb = (bid & 7) * 1530 + (bid >> 3);
    const int bq = sb * 2 + j;
    const int b = bq >= LQT;
    const int q = bq - b * LQT;
    int lvl0, start0, S0;
    level_of(q, lvl0, start0, S0);
    const int qi = q - start0;
    {
        const int lv = (tt >> 2) & 3;
        const int SL[4]  = {96, 48, 24, 12};
        const int STL[4] = {0, 9216, 11520, 12096};
        const int S = SL[lv];
        const float refx = ((float)(qi % S0) + 0.5f) / (float)S0;
        const float refy = ((float)(qi / S0) + 0.5f) / (float)S0;
        const unsigned int ou = *(const unsigned int*)(off + (long)bq * 256 + 2 * tt);
        const float x = refx * (float)S - 0.5f + bf2f((unsigned short)(ou & 0xffffu));
        const float y = refy * (float)S - 0.5f + bf2f((unsigned short)(ou >> 16));
        const float logit = aw[(long)bq * 128 + tt];
        float mx = logit;
        #pragma unroll
        for (int s_ = 1; s_ < 16; s_ <<= 1) mx = fmaxf(mx, __shfl_xor(mx, s_));
        const float e = __expf(logit - mx);
        float sum = e;
        #pragma unroll
        for (int s_ = 1; s_ < 16; s_ <<= 1) sum += __shfl_xor(sum, s_);
        const float wat = e / sum;
        const float x0 = floorf(x), y0 = floorf(y);
        const float tx = x - x0, ty = y - y0;
        const int ix = (int)x0, iy = (int)y0;
        #pragma unroll
        for (int c = 0; c < 4; ++c) {
            const int dx = c & 1, dy = c >> 1;
            const int xi = ix + dx, yi = iy + dy;
            const bool ok = (xi >= 0) && (xi < S) && (yi >= 0) && (yi < S);
            const int cx = min(max(xi, 0), S - 1);
            const int cy = min(max(yi, 0), S - 1);
            const float wxy = (dx ? tx : 1.f - tx) * (dy ? ty : 1.f - ty);
            s_base[j][tt][c] = (STL[lv] + cy * S + cx) * 256;
            s_w[j][tt][c] = ok ? wxy * wat : 0.f;
        }
    }
    __syncthreads();
    const int h = tt >> 4, d8 = (tt >> 2) & 3, sub = tt & 3;
    const unsigned short* vb = val + (long)b * (LQT * DD) + h * 32 + d8 * 8;
    float a0 = 0.f, a1 = 0.f, a2 = 0.f, a3 = 0.f;
    float a4 = 0.f, a5 = 0.f, a6 = 0.f, a7 = 0.f;
    #pragma unroll
    for (int i = 0; i < 4; ++i) {
        const int task = h * 16 + i * 4 + sub;
        #pragma unroll
        for (int c = 0; c < 4; ++c) {
            const float wv = s_w[j][task][c];
            const uint4 g = *(const uint4*)(vb + s_base[j][task][c]);
            a0 = fmaf(wv, bf2f((unsigned short)(g.x & 0xffffu)), a0);
            a1 = fmaf(wv, bf2f((unsigned short)(g.x >> 16)), a1);
            a2 = fmaf(wv, bf2f((unsigned short)(g.y & 0xffffu)), a2);
            a3 = fmaf(wv, bf2f((unsigned short)(g.y >> 16)), a3);
            a4 = fmaf(wv, bf2f((unsigned short)(g.z & 0xffffu)), a4);
            a5 = fmaf(wv, bf2f((unsigned short)(g.z >> 16)), a5);
            a6 = fmaf(wv, bf2f((unsigned short)(g.w & 0xffffu)), a6);
            a7 = fmaf(wv, bf2f((unsigned short)(g.w >> 16)), a7);
        }
    }
    #pragma unroll
    for (int o = 1; o < 4; o <<= 1) {
        a0 += __shfl_xor(a0, o); a1 += __shfl_xor(a1, o);
        a2 += __shfl_xor(a2, o); a3 += __shfl_xor(a3, o);
        a4 += __shfl_xor(a4, o); a5 += __shfl_xor(a5, o);
        a6 += __shfl_xor(a6, o); a7 += __shfl_xor(a7, o);
    }
    if (sub == 0) {
        uint4 o;
        o.x = (unsigned)f2bf(a0) | ((unsigned)f2bf(a1) << 16);
        o.y = (unsigned)f2bf(a2) | ((unsigned)f2bf(a3) << 16);
        o.z = (unsigned)f2bf(a4) | ((unsigned)f2bf(a5) << 16);
        o.w = (unsigned)f2bf(a6) | ((unsigned)f2bf(a7) << 16);
        *(uint4*)(out + (long)bq * DD + h * 32 + d8 * 8) = o;
    }
}

// Fused conversion of ALL weights (10 segments, contiguous dst)
#define WCVT_TOTAL 5177344L
__global__ __launch_bounds__(256)
void wcvt_k(const float* __restrict__ s0, const float* __restrict__ s1,
            const float* __restrict__ s2, const float* __restrict__ s3,
            const float* __restrict__ s4, const float* __restrict__ s5,
            const float* __restrict__ s6, const float* __restrict__ s7,
            const float* __restrict__ s8, const float* __restrict__ s9,
            unsigned short* __restrict__ dst)
{
    const long i = ((long)blockIdx.x * 256 + threadIdx.x) * 4;
    if (i >= WCVT_TOTAL) return;
    const float* sp; long base;
    if (i < 1048576) {
        if (i < 655360) {
            if (i < 65536)       { sp = s0; base = 0; }
            else if (i < 196608) { sp = s1; base = 65536; }
            else if (i < 393216) { sp = s2; base = 196608; }
            else                 { sp = s3; base = 393216; }
        } else                   { sp = s4; base = 655360; }
    } else if (i < 2031616) {
        if (i < 1245184)         { sp = s5; base = 1048576; }
        else if (i < 1638400)    { sp = s6; base = 1245184; }
        else                     { sp = s7; base = 1638400; }
    } else if (i < 3604480)      { sp = s8; base = 2031616; }
    else                         { sp = s9; base = 3604480; }
    const float4 v = *(const float4*)(sp + (i - base));
    ushort4 o;
    o.x = f2bf(v.x); o.y = f2bf(v.y); o.z = f2bf(v.z); o.w = f2bf(v.w);
    *(ushort4*)(dst + i) = o;
}

__global__ void tail_k(float* __restrict__ o)
{
    const float tv[28] = {0.f, 9216.f, 11520.f, 12096.f,
                          96.f, 96.f, 48.f, 48.f, 24.f, 24.f, 12.f, 12.f,
                          1.f, 1.f, 1.f, 1.f, 1.f, 1.f, 1.f, 1.f,
                          1.f, 1.f, 1.f, 1.f, 1.f, 1.f, 1.f, 1.f};
    const int t = threadIdx.x;
    if (t < 28) o[t] = tv[t];
}

extern "C" void kernel_launch(void* const* d_in, const int* in_sizes, int n_in,
                              void* d_out, int out_size, void* d_ws, size_t ws_size,
                              hipStream_t stream)
{
    const float* xs[4]  = {(const float*)d_in[0], (const float*)d_in[3],
                           (const float*)d_in[6], (const float*)d_in[9]};
    const float* fcw[4] = {(const float*)d_in[1], (const float*)d_in[4],
                           (const float*)d_in[7], (const float*)d_in[10]};
    const float* fcb[4] = {(const float*)d_in[2], (const float*)d_in[5],
                           (const float*)d_in[8], (const float*)d_in[11]};
    const float* gn_g = (const float*)d_in[12];
    const float* gn_b = (const float*)d_in[13];
    const float* lemb = (const float*)d_in[14];
    const float* off_w = (const float*)d_in[15];
    const float* off_b = (const float*)d_in[16];
    const float* aw_w  = (const float*)d_in[17];
    const float* aw_b  = (const float*)d_in[18];
    const float* val_w = (const float*)d_in[19];
    const float* val_b = (const float*)d_in[20];
    const float* out_w = (const float*)d_in[21];
    const float* out_b = (const float*)d_in[22];
    const float* ln1_g = (const float*)d_in[23];
    const float* ln1_b = (const float*)d_in[24];
    const float* l1_w  = (const float*)d_in[25];
    const float* l1_b  = (const float*)d_in[26];
    const float* l2_w  = (const float*)d_in[27];
    const float* l2_b  = (const float*)d_in[28];
    const float* ln2_g = (const float*)d_in[29];
    const float* ln2_b = (const float*)d_in[30];

    float* src = (float*)d_out;                 // (B, LQ, D) final f32 out
    float* ws = (float*)d_ws;
    float* pos = ws;                            // 3,133,440 f32
    float* awb = pos + 3133440;                 // 3,133,440 f32 (aw logits)
    unsigned short* bigbuf = (unsigned short*)(awb + 3133440);
    unsigned short* xt     = bigbuf;            // setup only
    unsigned short* off_bf = bigbuf;
    unsigned short* val_bf = bigbuf + 6266880;
    unsigned short* msd_bf = bigbuf + 12533760;
    unsigned short* hid_bf = bigbuf;            // FFN hidden overlays all
    unsigned short* q_bf   = bigbuf + 25067520;
    unsigned short* src_bf = q_bf + 6266880;
    unsigned short* wb     = src_bf + 6266880;
    unsigned short* wb_fc[4];
    wb_fc[0] = wb;
    wb_fc[1] = wb_fc[0] + 65536;
    wb_fc[2] = wb_fc[1] + 131072;
    wb_fc[3] = wb_fc[2] + 196608;
    unsigned short* wb_off = wb_fc[3] + 262144;
    unsigned short* wb_aw  = wb_off + 393216;
    unsigned short* wb_val = wb_aw  + 196608;
    unsigned short* wb_out = wb_val + 393216;
    unsigned short* wb_l1  = wb_out + 393216;
    unsigned short* wb_l2  = wb_l1  + 1572864;
    float* part = (float*)(wb_l2 + 1572864);    // 16384 f32
    float* stat = part + 16384;                 // 512 f32
    (void)in_sizes; (void)n_in; (void)out_size; (void)ws_size;

    const int CINS[4]   = {256, 512, 768, 1024};
    const int SS[4]     = {96, 48, 24, 12};
    const int STARTS[4] = {0, 9216, 11520, 12096};
    const long XTOFF[4] = {0, 4718592, 7077888, 7962624};

    // 0) positional embedding + all weights -> bf16 (one kernel)
    pos_k<<<LQT, 256, 0, stream>>>(pos, lemb);
    wcvt_k<<<(WCVT_TOTAL / 4 + 255) / 256, 256, 0, stream>>>(
        fcw[0], fcw[1], fcw[2], fcw[3], off_w, aw_w, val_w, out_w, l1_w, l2_w, wb);

    // 1) transpose inputs + bf16 projections (f32 out into src)
    for (int i = 0; i < 4; ++i) {
        const int Ml = SS[i] * SS[i];
        tp_k<<<dim3((Ml + 31) / 32, CINS[i] / 32, BB), 256, 0, stream>>>(
            xs[i], xt + XTOFF[i], CINS[i], Ml);
    }
    for (int i = 0; i < 4; ++i) {
        const int Ml = SS[i] * SS[i];
        gemm64<<<dim3((Ml + 63) / 64, 2, BB), 256, 0, stream>>>(
            xt + XTOFF[i], (long)Ml * CINS[i],
            wb_fc[i], fcb[i],
            src + (long)STARTS[i] * DD, (long)LQT * DD,
            Ml, DD, CINS[i]);
    }
    // 2) group norm (3-phase) -> src_bf + q_bf
    gn_part<<<256, 256, 0, stream>>>(src, part);
    gn_fin<<<1, 256, 0, stream>>>(part, stat);
    gn_apply<<<MROWS / 4, 256, 0, stream>>>(src, src_bf, q_bf, stat, gn_g, gn_b, pos);

    // 3) encoder layers (BK=64 GEMMs: fewer, fatter K-steps)
    const size_t lnLds = 75008;
    for (int l = 0; l < 6; ++l) {
        gemm_qkv<<<dim3(383, 5), 256, 0, stream>>>(
            q_bf, src_bf,
            wb_off + (long)l * 65536, wb_aw + (long)l * 32768,
            wb_val + (long)l * 65536,
            off_b + l * DD, aw_b + l * 128, val_b + l * DD,
            awb, off_bf, val_bf);
        msdeform_k<<<MROWS / 2, 256, 0, stream>>>(val_bf, off_bf, awb, msd_bf);
        // out-proj + bf16 residual + LN1 -> src_bf (K=256, 4 steps)
        gemm_ln<<<765, 256, lnLds, stream>>>(
            msd_bf, wb_out + (long)l * 65536, out_b + l * DD, src_bf,
            ln1_g + l * DD, ln1_b + l * DD, nullptr, src_bf,
            nullptr, nullptr, MROWS, DD);
        gemm128<<<dim3(192, 8), 256, 0, stream>>>(
            src_bf, wb_l1 + (long)l * 262144, l1_b + l * DFFN, hid_bf,
            MROWS, DFFN, DD);
        // ffn2 + bf16 residual + LN2 (+ next q) (K=1024, 16 steps)
        const bool last = (l == 5);
        gemm_ln<<<765, 256, lnLds, stream>>>(
            hid_bf, wb_l2 + (long)l * 262144, l2_b + l * DD, src_bf,
            ln2_g + l * DD, ln2_b + l * DD, last ? src : nullptr, src_bf,
            last ? nullptr : pos, last ? nullptr : q_bf, MROWS, DFFN);
    }
    // 4) constant tail outputs
    tail_k<<<1, 32, 0, stream>>>(src + (long)BB * LQT * DD);
}

// Round 15
// 1572.513 us; speedup vs baseline: 1.1998x; 1.0664x over previous
//
#include <hip/hip_runtime.h>
#include <math.h>

#define DD 256
#define DFFN 1024
#define LQT 12240
#define BB 2
#define MROWS (BB * LQT)   // 24480

typedef __attribute__((ext_vector_type(8))) short short8v;
typedef __attribute__((ext_vector_type(4))) float floatx4;

__device__ __forceinline__ unsigned short f2bf(float x) {
    unsigned int u = __builtin_bit_cast(unsigned int, x);
    u = (u + 0x7fffu + ((u >> 16) & 1u)) >> 16;
    return (unsigned short)u;
}
__device__ __forceinline__ float bf2f(unsigned short h) {
    unsigned int u = ((unsigned int)h) << 16;
    return __builtin_bit_cast(float, u);
}

__device__ __forceinline__ void gload16(const unsigned short* g, unsigned short* lds) {
    __builtin_amdgcn_global_load_lds(
        (const __attribute__((address_space(1))) unsigned int*)g,
        (__attribute__((address_space(3))) unsigned int*)lds, 16, 0, 0);
}

__device__ __forceinline__ void level_of(int q, int& lvl, int& start, int& S) {
    if (q < 9216)       { lvl = 0; start = 0;     S = 96; }
    else if (q < 11520) { lvl = 1; start = 9216;  S = 48; }
    else if (q < 12096) { lvl = 2; start = 11520; S = 24; }
    else                { lvl = 3; start = 12096; S = 12; }
}

// ---------------------------------------------------------------------------
// Merged QKV projection: grid (383, 5), 256t, 2-phase double-buffer (R7).
// ---------------------------------------------------------------------------
__global__ __launch_bounds__(256)
void gemm_qkv(const unsigned short* __restrict__ Aq,
              const unsigned short* __restrict__ Asr,
              const unsigned short* __restrict__ Woff,
              const unsigned short* __restrict__ Waw,
              const unsigned short* __restrict__ Wval,
              const float* __restrict__ boff, const float* __restrict__ baw,
              const float* __restrict__ bval,
              float* __restrict__ awbo, unsigned short* __restrict__ offo,
              unsigned short* __restrict__ valo)
{
    __shared__ alignas(16) unsigned short As[2][4][64][8];
    __shared__ alignas(16) unsigned short Bs[2][4][128][8];
    const int t = threadIdx.x;
    const int m0 = blockIdx.x * 64;
    const int y = blockIdx.y;
    const unsigned short* A; const unsigned short* Wb; const float* bi;
    int nb, mode;
    if (y < 3) {
        A = Aq;
        if (y < 2) { Wb = Woff; bi = boff; nb = y * 128; mode = 0; }
        else       { Wb = Waw;  bi = baw;  nb = 0;       mode = 1; }
    } else {
        A = Asr; Wb = Wval; bi = bval; nb = (y - 3) * 128; mode = 2;
    }
    const int wv = __builtin_amdgcn_readfirstlane(t >> 6);
    const int lane = t & 63;
    const int wm = wv >> 1, wn = wv & 1;
    const int kb = lane >> 4, lr = lane & 15;

    const int ar = min(m0 + lane, MROWS - 1);
    const unsigned short* gA  = A  + (long)ar * 256 + wv * 8;
    const unsigned short* gB0 = Wb + (long)(nb + lane) * 256 + wv * 8;
    const unsigned short* gB1 = Wb + (long)(nb + 64 + lane) * 256 + wv * 8;

    floatx4 acc[2][4];
    #pragma unroll
    for (int m = 0; m < 2; ++m)
        #pragma unroll
        for (int n = 0; n < 4; ++n)
            acc[m][n] = (floatx4){0.f, 0.f, 0.f, 0.f};

    gload16(gA,  &As[0][wv][0][0]);
    gload16(gB0, &Bs[0][wv][0][0]);
    gload16(gB1, &Bs[0][wv][64][0]);
    gA += 32; gB0 += 32; gB1 += 32;
    __syncthreads();

    #pragma unroll
    for (int kt = 0; kt < 8; ++kt) {
        const int cur = kt & 1;
        if (kt < 7) {
            gload16(gA,  &As[cur ^ 1][wv][0][0]);
            gload16(gB0, &Bs[cur ^ 1][wv][0][0]);
            gload16(gB1, &Bs[cur ^ 1][wv][64][0]);
            gA += 32; gB0 += 32; gB1 += 32;
        }
        short8v av[2], bv[4];
        #pragma unroll
        for (int m = 0; m < 2; ++m)
            av[m] = *(const short8v*)&As[cur][kb][wm * 32 + m * 16 + lr][0];
        #pragma unroll
        for (int n = 0; n < 4; ++n)
            bv[n] = *(const short8v*)&Bs[cur][kb][wn * 64 + n * 16 + lr][0];
        #pragma unroll
        for (int m = 0; m < 2; ++m)
            #pragma unroll
            for (int n = 0; n < 4; ++n)
                acc[m][n] = __builtin_amdgcn_mfma_f32_16x16x32_bf16(
                    av[m], bv[n], acc[m][n], 0, 0, 0);
        __syncthreads();
    }

    const int lh = lane >> 4;
    #pragma unroll
    for (int m = 0; m < 2; ++m) {
        const int row0 = m0 + wm * 32 + m * 16 + lh * 4;
        #pragma unroll
        for (int n = 0; n < 4; ++n) {
            const int col = nb + wn * 64 + n * 16 + lr;
            const float b = bi[col];
            #pragma unroll
            for (int r = 0; r < 4; ++r) {
                const int row = row0 + r;
                if (row >= MROWS) continue;
                const float v = acc[m][n][r] + b;
                if (mode == 0)      offo[(long)row * 256 + col] = f2bf(v);
                else if (mode == 1) awbo[(long)row * 128 + col] = v;
                else                valo[(long)row * 256 + col] = f2bf(v);
            }
        }
    }
}

// ---------------------------------------------------------------------------
// BM=64 x BN=128 bf16 GEMM (input projections only, setup), 2-phase
// ---------------------------------------------------------------------------
__global__ __launch_bounds__(256)
void gemm64(const unsigned short* __restrict__ A, long aZ,
            const unsigned short* __restrict__ W,
            const float* __restrict__ bias,
            float* __restrict__ Cf, long cZ,
            int M, int N, int K)
{
    __shared__ alignas(16) unsigned short As[2][4][64][8];
    __shared__ alignas(16) unsigned short Bs[2][4][128][8];
    const int t = threadIdx.x;
    const int z = blockIdx.z;
    A  += (long)z * aZ;
    Cf += (long)z * cZ;
    const int m0 = blockIdx.x * 64;
    const int n0 = blockIdx.y * 128;
    const int wv = __builtin_amdgcn_readfirstlane(t >> 6);
    const int lane = t & 63;
    const int wm = wv >> 1, wn = wv & 1;
    const int kb = lane >> 4, lr = lane & 15;

    const int ar = min(m0 + lane, M - 1);
    const unsigned short* gA  = A + (long)ar * K + wv * 8;
    const unsigned short* gB0 = W + (long)(n0 + lane) * K + wv * 8;
    const unsigned short* gB1 = W + (long)(n0 + 64 + lane) * K + wv * 8;

    floatx4 acc[2][4];
    #pragma unroll
    for (int m = 0; m < 2; ++m)
        #pragma unroll
        for (int n = 0; n < 4; ++n)
            acc[m][n] = (floatx4){0.f, 0.f, 0.f, 0.f};

    gload16(gA,  &As[0][wv][0][0]);
    gload16(gB0, &Bs[0][wv][0][0]);
    gload16(gB1, &Bs[0][wv][64][0]);
    gA += 32; gB0 += 32; gB1 += 32;
    __syncthreads();

    const int nk = K >> 5;
    for (int kt = 0; kt < nk; ++kt) {
        const int cur = kt & 1;
        if (kt + 1 < nk) {
            gload16(gA,  &As[cur ^ 1][wv][0][0]);
            gload16(gB0, &Bs[cur ^ 1][wv][0][0]);
            gload16(gB1, &Bs[cur ^ 1][wv][64][0]);
            gA += 32; gB0 += 32; gB1 += 32;
        }
        short8v av[2], bv[4];
        #pragma unroll
        for (int m = 0; m < 2; ++m)
            av[m] = *(const short8v*)&As[cur][kb][wm * 32 + m * 16 + lr][0];
        #pragma unroll
        for (int n = 0; n < 4; ++n)
            bv[n] = *(const short8v*)&Bs[cur][kb][wn * 64 + n * 16 + lr][0];
        #pragma unroll
        for (int m = 0; m < 2; ++m)
            #pragma unroll
            for (int n = 0; n < 4; ++n)
                acc[m][n] = __builtin_amdgcn_mfma_f32_16x16x32_bf16(
                    av[m], bv[n], acc[m][n], 0, 0, 0);
        __syncthreads();
    }

    const int lh = lane >> 4;
    #pragma unroll
    for (int m = 0; m < 2; ++m) {
        const int row0 = m0 + wm * 32 + m * 16 + lh * 4;
        #pragma unroll
        for (int n = 0; n < 4; ++n) {
            const int col = n0 + wn * 64 + n * 16 + lr;
            const float b = bias[col];
            #pragma unroll
            for (int r = 0; r < 4; ++r) {
                const int row = row0 + r;
                if (row >= M) continue;
                Cf[(long)row * N + col] = acc[m][n][r] + b;
            }
        }
    }
}

// ---------------------------------------------------------------------------
// FFN1 BM=128 x BN=128 (relu -> bf16), 2-phase (R7)
// ---------------------------------------------------------------------------
__global__ __launch_bounds__(256)
void gemm128(const unsigned short* __restrict__ A,
             const unsigned short* __restrict__ W,
             const float* __restrict__ bias, unsigned short* __restrict__ Ch,
             int M, int N, int K)
{
    __shared__ alignas(16) unsigned short As[2][4][128][8];
    __shared__ alignas(16) unsigned short Bs[2][4][128][8];
    const int t = threadIdx.x;
    const int m0 = blockIdx.x * 128;
    const int n0 = blockIdx.y * 128;
    const int wv = __builtin_amdgcn_readfirstlane(t >> 6);
    const int lane = t & 63;
    const int wm = wv >> 1, wn = wv & 1;
    const int kb = lane >> 4, lr = lane & 15;

    const int r0 = min(m0 + lane, M - 1);
    const int r1 = min(m0 + 64 + lane, M - 1);
    const unsigned short* gA0 = A + (long)r0 * K + wv * 8;
    const unsigned short* gA1 = A + (long)r1 * K + wv * 8;
    const unsigned short* gB0 = W + (long)(n0 + lane) * K + wv * 8;
    const unsigned short* gB1 = W + (long)(n0 + 64 + lane) * K + wv * 8;

    floatx4 acc[4][4];
    #pragma unroll
    for (int m = 0; m < 4; ++m)
        #pragma unroll
        for (int n = 0; n < 4; ++n)
            acc[m][n] = (floatx4){0.f, 0.f, 0.f, 0.f};

    gload16(gA0, &As[0][wv][0][0]);
    gload16(gA1, &As[0][wv][64][0]);
    gload16(gB0, &Bs[0][wv][0][0]);
    gload16(gB1, &Bs[0][wv][64][0]);
    gA0 += 32; gA1 += 32; gB0 += 32; gB1 += 32;
    __syncthreads();

    const int nk = K >> 5;
    for (int kt = 0; kt < nk; ++kt) {
        const int cur = kt & 1;
        if (kt + 1 < nk) {
            gload16(gA0, &As[cur ^ 1][wv][0][0]);
            gload16(gA1, &As[cur ^ 1][wv][64][0]);
            gload16(gB0, &Bs[cur ^ 1][wv][0][0]);
            gload16(gB1, &Bs[cur ^ 1][wv][64][0]);
            gA0 += 32; gA1 += 32; gB0 += 32; gB1 += 32;
        }
        short8v av[4], bv[4];
        #pragma unroll
        for (int m = 0; m < 4; ++m)
            av[m] = *(const short8v*)&As[cur][kb][wm * 64 + m * 16 + lr][0];
        #pragma unroll
        for (int n = 0; n < 4; ++n)
            bv[n] = *(const short8v*)&Bs[cur][kb][wn * 64 + n * 16 + lr][0];
        #pragma unroll
        for (int m = 0; m < 4; ++m)
            #pragma unroll
            for (int n = 0; n < 4; ++n)
                acc[m][n] = __builtin_amdgcn_mfma_f32_16x16x32_bf16(
                    av[m], bv[n], acc[m][n], 0, 0, 0);
        __syncthreads();
    }

    const int lh = lane >> 4;
    #pragma unroll
    for (int m = 0; m < 4; ++m) {
        const int row0 = m0 + wm * 64 + m * 16 + lh * 4;
        #pragma unroll
        for (int n = 0; n < 4; ++n) {
            const int col = n0 + wn * 64 + n * 16 + lr;
            const float b = bias[col];
            #pragma unroll
            for (int r = 0; r < 4; ++r) {
                const int row = row0 + r;
                if (row >= M) continue;
                Ch[(long)row * N + col] = f2bf(fmaxf(acc[m][n][r] + b, 0.f));
            }
        }
    }
}

// ---------------------------------------------------------------------------
// BM=32 x BN=256 GEMM + bias + bf16-residual + LayerNorm epilogue (R7).
// pos read as bf16; outh optional (dead on last layer).
// ---------------------------------------------------------------------------
__global__ __launch_bounds__(256)
void gemm_ln(const unsigned short* __restrict__ A,
             const unsigned short* __restrict__ W,
             const float* __restrict__ bias, const unsigned short* R,
             const float* __restrict__ lg, const float* __restrict__ lb,
             float* outf, unsigned short* outh,
             const unsigned short* __restrict__ pos_bf,
             unsigned short* __restrict__ qout,
             int M, int K)
{
    __shared__ alignas(16) unsigned short As[2][4][32][8];
    __shared__ alignas(16) unsigned short Bs[2][4][256][8];
    __shared__ float red[32][4][2];
    __shared__ float smean[32], sinv[32];
    const int t = threadIdx.x;
    const int m0 = blockIdx.x * 32;
    const int wv = __builtin_amdgcn_readfirstlane(t >> 6);
    const int lane = t & 63;
    const int kb = lane >> 4, lr = lane & 15;
    const int lh = kb;

    const unsigned short* gA = A + (long)(m0 + (lane & 31)) * K
                                 + (wv * 2 + (lane >> 5)) * 8;
    const unsigned short* gB0 = W + (long)lane * K + wv * 8;
    const unsigned short* gB1 = W + (long)(64 + lane) * K + wv * 8;
    const unsigned short* gB2 = W + (long)(128 + lane) * K + wv * 8;
    const unsigned short* gB3 = W + (long)(192 + lane) * K + wv * 8;

    floatx4 acc[2][4];
    #pragma unroll
    for (int m = 0; m < 2; ++m)
        #pragma unroll
        for (int n = 0; n < 4; ++n)
            acc[m][n] = (floatx4){0.f, 0.f, 0.f, 0.f};

    if (wv < 2) gload16(gA, &As[0][wv * 2][0][0]);
    gload16(gB0, &Bs[0][wv][0][0]);
    gload16(gB1, &Bs[0][wv][64][0]);
    gload16(gB2, &Bs[0][wv][128][0]);
    gload16(gB3, &Bs[0][wv][192][0]);
    gA += 32; gB0 += 32; gB1 += 32; gB2 += 32; gB3 += 32;
    __syncthreads();

    const int nk = K >> 5;
    for (int kt = 0; kt < nk; ++kt) {
        const int cur = kt & 1;
        if (kt + 1 < nk) {
            if (wv < 2) gload16(gA, &As[cur ^ 1][wv * 2][0][0]);
            gload16(gB0, &Bs[cur ^ 1][wv][0][0]);
            gload16(gB1, &Bs[cur ^ 1][wv][64][0]);
            gload16(gB2, &Bs[cur ^ 1][wv][128][0]);
            gload16(gB3, &Bs[cur ^ 1][wv][192][0]);
            gA += 32; gB0 += 32; gB1 += 32; gB2 += 32; gB3 += 32;
        }
        short8v av[2], bv[4];
        #pragma unroll
        for (int m = 0; m < 2; ++m)
            av[m] = *(const short8v*)&As[cur][kb][m * 16 + lr][0];
        #pragma unroll
        for (int n = 0; n < 4; ++n)
            bv[n] = *(const short8v*)&Bs[cur][kb][wv * 64 + n * 16 + lr][0];
        #pragma unroll
        for (int m = 0; m < 2; ++m)
            #pragma unroll
            for (int n = 0; n < 4; ++n)
                acc[m][n] = __builtin_amdgcn_mfma_f32_16x16x32_bf16(
                    av[m], bv[n], acc[m][n], 0, 0, 0);
        __syncthreads();
    }

    // bias + bf16 residual into acc
    #pragma unroll
    for (int n = 0; n < 4; ++n) {
        const int col = wv * 64 + n * 16 + lr;
        const float bcol = bias[col];
        #pragma unroll
        for (int m = 0; m < 2; ++m) {
            #pragma unroll
            for (int r = 0; r < 4; ++r) {
                const int grow = m0 + m * 16 + lh * 4 + r;
                acc[m][n][r] += bcol + bf2f(R[(long)grow * 256 + col]);
            }
        }
    }
    // per-row stats: sum over n, 16 lr lanes, then 4 waves via LDS
    #pragma unroll
    for (int m = 0; m < 2; ++m) {
        #pragma unroll
        for (int r = 0; r < 4; ++r) {
            float s = acc[m][0][r] + acc[m][1][r] + acc[m][2][r] + acc[m][3][r];
            float q = acc[m][0][r] * acc[m][0][r] + acc[m][1][r] * acc[m][1][r]
                    + acc[m][2][r] * acc[m][2][r] + acc[m][3][r] * acc[m][3][r];
            #pragma unroll
            for (int o = 1; o < 16; o <<= 1) {
                s += __shfl_xor(s, o);
                q += __shfl_xor(q, o);
            }
            if (lr == 0) {
                red[m * 16 + lh * 4 + r][wv][0] = s;
                red[m * 16 + lh * 4 + r][wv][1] = q;
            }
        }
    }
    __syncthreads();
    if (t < 32) {
        const float s = red[t][0][0] + red[t][1][0] + red[t][2][0] + red[t][3][0];
        const float q = red[t][0][1] + red[t][1][1] + red[t][2][1] + red[t][3][1];
        const float mean = s * (1.f / 256.f);
        smean[t] = mean;
        sinv[t] = rsqrtf(q * (1.f / 256.f) - mean * mean + 1e-5f);
    }
    __syncthreads();
    #pragma unroll
    for (int n = 0; n < 4; ++n) {
        const int col = wv * 64 + n * 16 + lr;
        const float gc = lg[col], bc = lb[col];
        #pragma unroll
        for (int m = 0; m < 2; ++m) {
            #pragma unroll
            for (int r = 0; r < 4; ++r) {
                const int row = m * 16 + lh * 4 + r;
                const int grow = m0 + row;
                const float y = (acc[m][n][r] - smean[row]) * sinv[row] * gc + bc;
                const long o = (long)grow * 256 + col;
                if (outh) outh[o] = f2bf(y);
                if (outf) outf[o] = y;
                if (qout) {
                    const int qrow = grow - (grow >= LQT ? LQT : 0);
                    qout[o] = f2bf(y + bf2f(pos_bf[(long)qrow * 256 + col]));
                }
            }
        }
    }
}

// ---------------------------------------------------------------------------
// transpose (C, Ml) f32 -> (Ml, C) bf16, batch via blockIdx.z
// ---------------------------------------------------------------------------
__global__ __launch_bounds__(256)
void tp_k(const float* __restrict__ x, unsigned short* __restrict__ xt,
          int C, int Ml)
{
    __shared__ float tile[32][33];
    const int m0 = blockIdx.x * 32, c0 = blockIdx.y * 32;
    const int zb = blockIdx.z;
    const float* px = x + (long)zb * C * Ml;
    unsigned short* pxt = xt + (long)zb * Ml * C;
    const int t = threadIdx.x;
    {
        const int cl = t >> 3, m4 = (t & 7) * 4;
        const int gm = m0 + m4;
        if (gm < Ml) {
            const float4 v = *(const float4*)(px + (long)(c0 + cl) * Ml + gm);
            tile[cl][m4 + 0] = v.x; tile[cl][m4 + 1] = v.y;
            tile[cl][m4 + 2] = v.z; tile[cl][m4 + 3] = v.w;
        }
    }
    __syncthreads();
    {
        const int ml = t >> 3, c4 = (t & 7) * 4;
        const int gm = m0 + ml;
        if (gm < Ml) {
            ushort4 o;
            o.x = f2bf(tile[c4 + 0][ml]);
            o.y = f2bf(tile[c4 + 1][ml]);
            o.z = f2bf(tile[c4 + 2][ml]);
            o.w = f2bf(tile[c4 + 3][ml]);
            *(ushort4*)(pxt + (long)gm * C + c0 + c4) = o;
        }
    }
}

// ---------------------------------------------------------------------------
// GroupNorm 3-phase
// ---------------------------------------------------------------------------
__global__ __launch_bounds__(256)
void gn_part(const float* __restrict__ src, float* __restrict__ part)
{
    const int x = blockIdx.x;
    const int b = x >> 7, c = x & 127;
    int lvl, chunk;
    if (c < 96)       { lvl = 0; chunk = c; }
    else if (c < 120) { lvl = 1; chunk = c - 96; }
    else if (c < 126) { lvl = 2; chunk = c - 120; }
    else              { lvl = 3; chunk = c - 126; }
    const int starts[4] = {0, 9216, 11520, 12096};
    const int crows[4]  = {96, 96, 96, 72};
    const int rows = crows[lvl];
    const long base = ((long)b * LQT + starts[lvl] + (long)chunk * rows) * DD;
    const int t = threadIdx.x;
    float s = 0.f, sq = 0.f;
    for (int r = 0; r < rows; ++r) {
        const float v = src[base + (long)r * DD + t];
        s += v; sq += v * v;
    }
    #pragma unroll
    for (int o = 1; o < 8; o <<= 1) {
        s  += __shfl_xor(s, o);
        sq += __shfl_xor(sq, o);
    }
    if ((t & 7) == 0) {
        float* p = part + ((long)x * 32 + (t >> 3)) * 2;
        p[0] = s; p[1] = sq;
    }
}

__global__ void gn_fin(const float* __restrict__ part, float* __restrict__ stat)
{
    const int t = threadIdx.x;
    const int b = t >> 7, rest = t & 127;
    const int lvl = rest >> 5, grp = rest & 31;
    const int cbase[4] = {0, 96, 120, 126};
    const int ccnt[4]  = {96, 24, 6, 2};
    const int Ml[4]    = {9216, 2304, 576, 144};
    float s = 0.f, sq = 0.f;
    for (int i = 0; i < ccnt[lvl]; ++i) {
        const float* p = part + ((long)(b * 128 + cbase[lvl] + i) * 32 + grp) * 2;
        s += p[0]; sq += p[1];
    }
    const float cnt = (float)(Ml[lvl] * 8);
    const float mean = s / cnt;
    const float inv = rsqrtf(sq / cnt - mean * mean + 1e-5f);
    float* o = stat + ((b * 4 + lvl) * 32 + grp) * 2;
    o[0] = mean; o[1] = inv;
}

__global__ __launch_bounds__(256)
void gn_apply(const float* __restrict__ src, unsigned short* __restrict__ srch,
              unsigned short* __restrict__ qout,
              const float* __restrict__ stat,
              const float* __restrict__ gg, const float* __restrict__ gb,
              const unsigned short* __restrict__ pos_bf)
{
    const int t = threadIdx.x;
    const long row = (long)blockIdx.x * 4 + (t >> 6);
    const int lane = t & 63;
    const int b = row >= LQT;
    const int q = (int)row - b * LQT;
    int lvl, start, S;
    level_of(q, lvl, start, S);
    const float2 ms = *(const float2*)(stat + ((b * 4 + lvl) * 32 + (lane >> 1)) * 2);
    const int col = lane * 4;
    const float4 v  = *(const float4*)(src + row * DD + col);
    const float4 gv = *(const float4*)(gg + lvl * DD + col);
    const float4 bv = *(const float4*)(gb + lvl * DD + col);
    float4 y;
    y.x = (v.x - ms.x) * ms.y * gv.x + bv.x;
    y.y = (v.y - ms.x) * ms.y * gv.y + bv.y;
    y.z = (v.z - ms.x) * ms.y * gv.z + bv.z;
    y.w = (v.w - ms.x) * ms.y * gv.w + bv.w;
    ushort4 hh;
    hh.x = f2bf(y.x); hh.y = f2bf(y.y); hh.z = f2bf(y.z); hh.w = f2bf(y.w);
    *(ushort4*)(srch + row * DD + col) = hh;
    const ushort4 pv = *(const ushort4*)(pos_bf + (long)q * DD + col);
    ushort4 qq;
    qq.x = f2bf(y.x + bf2f(pv.x)); qq.y = f2bf(y.y + bf2f(pv.y));
    qq.z = f2bf(y.z + bf2f(pv.z)); qq.w = f2bf(y.w + bf2f(pv.w));
    *(ushort4*)(qout + row * DD + col) = qq;
}

__global__ __launch_bounds__(256)
void pos_k(unsigned short* __restrict__ pos_bf, const float* __restrict__ lemb)
{
    const int q = blockIdx.x;
    const int d = threadIdx.x;
    int lvl, start, S;
    level_of(q, lvl, start, S);
    const int qi = q - start;
    const int r = qi / S, c = qi % S;
    const float twopi = 6.283185307179586f;
    float e; int dd;
    if (d < 128) { e = (float)(r + 1) / ((float)S + 1e-6f) * twopi; dd = d; }
    else         { e = (float)(c + 1) / ((float)S + 1e-6f) * twopi; dd = d - 128; }
    const float dimt = expf(9.210340371976184f * (float)(dd & ~1) / 128.f);
    const float p = e / dimt;
    const float v = ((dd & 1) ? cosf(p) : sinf(p)) + lemb[lvl * DD + d];
    pos_bf[(long)q * DD + d] = f2bf(v);
}

// ---------------------------------------------------------------------------
// Deformable attention: XCD-chunked block swizzle for L2 gather locality.
// ---------------------------------------------------------------------------
__global__ __launch_bounds__(256)
void msdeform_k(const unsigned short* __restrict__ val,
                const unsigned short* __restrict__ off,
                const float* __restrict__ aw,
                unsigned short* __restrict__ out)
{
    __shared__ int   s_base[2][128][5];
    __shared__ float s_w[2][128][5];
    const int t = threadIdx.x;
    const int j = t >> 7;
    const int tt = t & 127;
    const int bid = blockIdx.x;
    const int sb = (bid & 7) * 1530 + (bid >> 3);
    const int bq = sb * 2 + j;
    const int b = bq >= LQT;
    const int q = bq - b * LQT;
    int lvl0, start0, S0;
    level_of(q, lvl0, start0, S0);
    const int qi = q - start0;
    {
        const int lv = (tt >> 2) & 3;
        const int SL[4]  = {96, 48, 24, 12};
        const int STL[4] = {0, 9216, 11520, 12096};
        const int S = SL[lv];
        const float refx = ((float)(qi % S0) + 0.5f) / (float)S0;
        const float refy = ((float)(qi / S0) + 0.5f) / (float)S0;
        const unsigned int ou = *(const unsigned int*)(off + (long)bq * 256 + 2 * tt);
        const float x = refx * (float)S - 0.5f + bf2f((unsigned short)(ou & 0xffffu));
        const float y = refy * (float)S - 0.5f + bf2f((unsigned short)(ou >> 16));
        const float logit = aw[(long)bq * 128 + tt];
        float mx = logit;
        #pragma unroll
        for (int s_ = 1; s_ < 16; s_ <<= 1) mx = fmaxf(mx, __shfl_xor(mx, s_));
        const float e = __expf(logit - mx);
        float sum = e;
        #pragma unroll
        for (int s_ = 1; s_ < 16; s_ <<= 1) sum += __shfl_xor(sum, s_);
        const float wat = e / sum;
        const float x0 = floorf(x), y0 = floorf(y);
        const float tx = x - x0, ty = y - y0;
        const int ix = (int)x0, iy = (int)y0;
        #pragma unroll
        for (int c = 0; c < 4; ++c) {
            const int dx = c & 1, dy = c >> 1;
            const int xi = ix + dx, yi = iy + dy;
            const bool ok = (xi >= 0) && (xi < S) && (yi >= 0) && (yi < S);
            const int cx = min(max(xi, 0), S - 1);
            const int cy = min(max(yi, 0), S - 1);
            const float wxy = (dx ? tx : 1.f - tx) * (dy ? ty : 1.f - ty);
            s_base[j][tt][c] = (STL[lv] + cy * S + cx) * 256;
            s_w[j][tt][c] = ok ? wxy * wat : 0.f;
        }
    }
    __syncthreads();
    const int h = tt >> 4, d8 = (tt >> 2) & 3, sub = tt & 3;
    const unsigned short* vb = val + (long)b * (LQT * DD) + h * 32 + d8 * 8;
    float a0 = 0.f, a1 = 0.f, a2 = 0.f, a3 = 0.f;
    float a4 = 0.f, a5 = 0.f, a6 = 0.f, a7 = 0.f;
    #pragma unroll
    for (int i = 0; i < 4; ++i) {
        const int task = h * 16 + i * 4 + sub;
        #pragma unroll
        for (int c = 0; c < 4; ++c) {
            const float wv = s_w[j][task][c];
            const uint4 g = *(const uint4*)(vb + s_base[j][task][c]);
            a0 = fmaf(wv, bf2f((unsigned short)(g.x & 0xffffu)), a0);
            a1 = fmaf(wv, bf2f((unsigned short)(g.x >> 16)), a1);
            a2 = fmaf(wv, bf2f((unsigned short)(g.y & 0xffffu)), a2);
            a3 = fmaf(wv, bf2f((unsigned short)(g.y >> 16)), a3);
            a4 = fmaf(wv, bf2f((unsigned short)(g.z & 0xffffu)), a4);
            a5 = fmaf(wv, bf2f((unsigned short)(g.z >> 16)), a5);
            a6 = fmaf(wv, bf2f((unsigned short)(g.w & 0xffffu)), a6);
            a7 = fmaf(wv, bf2f((unsigned short)(g.w >> 16)), a7);
        }
    }
    #pragma unroll
    for (int o = 1; o < 4; o <<= 1) {
        a0 += __shfl_xor(a0, o); a1 += __shfl_xor(a1, o);
        a2 += __shfl_xor(a2, o); a3 += __shfl_xor(a3, o);
        a4 += __shfl_xor(a4, o); a5 += __shfl_xor(a5, o);
        a6 += __shfl_xor(a6, o); a7 += __shfl_xor(a7, o);
    }
    if (sub == 0) {
        uint4 o;
        o.x = (unsigned)f2bf(a0) | ((unsigned)f2bf(a1) << 16);
        o.y = (unsigned)f2bf(a2) | ((unsigned)f2bf(a3) << 16);
        o.z = (unsigned)f2bf(a4) | ((unsigned)f2bf(a5) << 16);
        o.w = (unsigned)f2bf(a6) | ((unsigned)f2bf(a7) << 16);
        *(uint4*)(out + (long)bq * DD + h * 32 + d8 * 8) = o;
    }
}

// Fused conversion of ALL weights (10 segments, contiguous dst)
#define WCVT_TOTAL 5177344L
__global__ __launch_bounds__(256)
void wcvt_k(const float* __restrict__ s0, const float* __restrict__ s1,
            const float* __restrict__ s2, const float* __restrict__ s3,
            const float* __restrict__ s4, const float* __restrict__ s5,
            const float* __restrict__ s6, const float* __restrict__ s7,
            const float* __restrict__ s8, const float* __restrict__ s9,
            unsigned short* __restrict__ dst)
{
    const long i = ((long)blockIdx.x * 256 + threadIdx.x) * 4;
    if (i >= WCVT_TOTAL) return;
    const float* sp; long base;
    if (i < 1048576) {
        if (i < 655360) {
            if (i < 65536)       { sp = s0; base = 0; }
            else if (i < 196608) { sp = s1; base = 65536; }
            else if (i < 393216) { sp = s2; base = 196608; }
            else                 { sp = s3; base = 393216; }
        } else                   { sp = s4; base = 655360; }
    } else if (i < 2031616) {
        if (i < 1245184)         { sp = s5; base = 1048576; }
        else if (i < 1638400)    { sp = s6; base = 1245184; }
        else                     { sp = s7; base = 1638400; }
    } else if (i < 3604480)      { sp = s8; base = 2031616; }
    else                         { sp = s9; base = 3604480; }
    const float4 v = *(const float4*)(sp + (i - base));
    ushort4 o;
    o.x = f2bf(v.x); o.y = f2bf(v.y); o.z = f2bf(v.z); o.w = f2bf(v.w);
    *(ushort4*)(dst + i) = o;
}

__global__ void tail_k(float* __restrict__ o)
{
    const float tv[28] = {0.f, 9216.f, 11520.f, 12096.f,
                          96.f, 96.f, 48.f, 48.f, 24.f, 24.f, 12.f, 12.f,
                          1.f, 1.f, 1.f, 1.f, 1.f, 1.f, 1.f, 1.f,
                          1.f, 1.f, 1.f, 1.f, 1.f, 1.f, 1.f, 1.f};
    const int t = threadIdx.x;
    if (t < 28) o[t] = tv[t];
}

extern "C" void kernel_launch(void* const* d_in, const int* in_sizes, int n_in,
                              void* d_out, int out_size, void* d_ws, size_t ws_size,
                              hipStream_t stream)
{
    const float* xs[4]  = {(const float*)d_in[0], (const float*)d_in[3],
                           (const float*)d_in[6], (const float*)d_in[9]};
    const float* fcw[4] = {(const float*)d_in[1], (const float*)d_in[4],
                           (const float*)d_in[7], (const float*)d_in[10]};
    const float* fcb[4] = {(const float*)d_in[2], (const float*)d_in[5],
                           (const float*)d_in[8], (const float*)d_in[11]};
    const float* gn_g = (const float*)d_in[12];
    const float* gn_b = (const float*)d_in[13];
    const float* lemb = (const float*)d_in[14];
    const float* off_w = (const float*)d_in[15];
    const float* off_b = (const float*)d_in[16];
    const float* aw_w  = (const float*)d_in[17];
    const float* aw_b  = (const float*)d_in[18];
    const float* val_w = (const float*)d_in[19];
    const float* val_b = (const float*)d_in[20];
    const float* out_w = (const float*)d_in[21];
    const float* out_b = (const float*)d_in[22];
    const float* ln1_g = (const float*)d_in[23];
    const float* ln1_b = (const float*)d_in[24];
    const float* l1_w  = (const float*)d_in[25];
    const float* l1_b  = (const float*)d_in[26];
    const float* l2_w  = (const float*)d_in[27];
    const float* l2_b  = (const float*)d_in[28];
    const float* ln2_g = (const float*)d_in[29];
    const float* ln2_b = (const float*)d_in[30];

    float* src = (float*)d_out;                 // (B, LQ, D) final f32 out
    float* ws = (float*)d_ws;
    unsigned short* pos_bf = (unsigned short*)ws;        // 3,133,440 ushort
    float* awb = ws + 1566720;                  // 3,133,440 f32 (aw logits)
    unsigned short* bigbuf = (unsigned short*)(awb + 3133440);
    unsigned short* xt     = bigbuf;            // setup only
    unsigned short* off_bf = bigbuf;
    unsigned short* val_bf = bigbuf + 6266880;
    unsigned short* msd_bf = bigbuf + 12533760;
    unsigned short* hid_bf = bigbuf;            // FFN hidden overlays all
    unsigned short* q_bf   = bigbuf + 25067520;
    unsigned short* src_bf = q_bf + 6266880;
    unsigned short* wb     = src_bf + 6266880;
    unsigned short* wb_fc[4];
    wb_fc[0] = wb;
    wb_fc[1] = wb_fc[0] + 65536;
    wb_fc[2] = wb_fc[1] + 131072;
    wb_fc[3] = wb_fc[2] + 196608;
    unsigned short* wb_off = wb_fc[3] + 262144;
    unsigned short* wb_aw  = wb_off + 393216;
    unsigned short* wb_val = wb_aw  + 196608;
    unsigned short* wb_out = wb_val + 393216;
    unsigned short* wb_l1  = wb_out + 393216;
    unsigned short* wb_l2  = wb_l1  + 1572864;
    float* part = (float*)(wb_l2 + 1572864);    // 16384 f32
    float* stat = part + 16384;                 // 512 f32
    (void)in_sizes; (void)n_in; (void)out_size; (void)ws_size;

    const int CINS[4]   = {256, 512, 768, 1024};
    const int SS[4]     = {96, 48, 24, 12};
    const int STARTS[4] = {0, 9216, 11520, 12096};
    const long XTOFF[4] = {0, 4718592, 7077888, 7962624};

    // 0) positional embedding (bf16) + all weights -> bf16 (one kernel)
    pos_k<<<LQT, 256, 0, stream>>>(pos_bf, lemb);
    wcvt_k<<<(WCVT_TOTAL / 4 + 255) / 256, 256, 0, stream>>>(
        fcw[0], fcw[1], fcw[2], fcw[3], off_w, aw_w, val_w, out_w, l1_w, l2_w, wb);

    // 1) transpose inputs + bf16 projections (f32 out into src)
    for (int i = 0; i < 4; ++i) {
        const int Ml = SS[i] * SS[i];
        tp_k<<<dim3((Ml + 31) / 32, CINS[i] / 32, BB), 256, 0, stream>>>(
            xs[i], xt + XTOFF[i], CINS[i], Ml);
    }
    for (int i = 0; i < 4; ++i) {
        const int Ml = SS[i] * SS[i];
        gemm64<<<dim3((Ml + 63) / 64, 2, BB), 256, 0, stream>>>(
            xt + XTOFF[i], (long)Ml * CINS[i],
            wb_fc[i], fcb[i],
            src + (long)STARTS[i] * DD, (long)LQT * DD,
            Ml, DD, CINS[i]);
    }
    // 2) group norm (3-phase) -> src_bf + q_bf
    gn_part<<<256, 256, 0, stream>>>(src, part);
    gn_fin<<<1, 256, 0, stream>>>(part, stat);
    gn_apply<<<MROWS / 4, 256, 0, stream>>>(src, src_bf, q_bf, stat, gn_g, gn_b, pos_bf);

    // 3) encoder layers
    for (int l = 0; l < 6; ++l) {
        gemm_qkv<<<dim3(383, 5), 256, 0, stream>>>(
            q_bf, src_bf,
            wb_off + (long)l * 65536, wb_aw + (long)l * 32768,
            wb_val + (long)l * 65536,
            off_b + l * DD, aw_b + l * 128, val_b + l * DD,
            awb, off_bf, val_bf);
        msdeform_k<<<MROWS / 2, 256, 0, stream>>>(val_bf, off_bf, awb, msd_bf);
        // out-proj + bf16 residual + LN1 -> src_bf
        gemm_ln<<<765, 256, 0, stream>>>(
            msd_bf, wb_out + (long)l * 65536, out_b + l * DD, src_bf,
            ln1_g + l * DD, ln1_b + l * DD, nullptr, src_bf,
            nullptr, nullptr, MROWS, DD);
        gemm128<<<dim3(192, 8), 256, 0, stream>>>(
            src_bf, wb_l1 + (long)l * 262144, l1_b + l * DFFN, hid_bf,
            MROWS, DFFN, DD);
        // ffn2 + bf16 residual + LN2 (+ next q); last layer: f32 out only
        const bool last = (l == 5);
        gemm_ln<<<765, 256, 0, stream>>>(
            hid_bf, wb_l2 + (long)l * 262144, l2_b + l * DD, src_bf,
            ln2_g + l * DD, ln2_b + l * DD,
            last ? src : nullptr, last ? nullptr : src_bf,
            last ? nullptr : pos_bf, last ? nullptr : q_bf, MROWS, DFFN);
    }
    // 4) constant tail outputs
    tail_k<<<1, 32, 0, stream>>>(src + (long)BB * LQT * DD);
}